// Round 1
// baseline (1312.094 us; speedup 1.0000x reference)
//
#include <hip/hip_runtime.h>
#include <hip/hip_bf16.h>

// WindowAttentionV2: B_NW=2048, N=64, DIM=512, NH=16, DH=32, HID=384, NW=64
// Pipeline: convert -> bias MLP -> fused qkv+cosine-attn -> out-proj GEMM.

typedef __bf16 bf16;
typedef __bf16 v4bf __attribute__((ext_vector_type(4)));
typedef __bf16 v8bf __attribute__((ext_vector_type(8)));
typedef float  v4f  __attribute__((ext_vector_type(4)));

// ---------------- K0a: x fp32 -> bf16 ----------------
__global__ void convert_x_kernel(const float* __restrict__ x, bf16* __restrict__ xbf) {
    size_t idx = (size_t)blockIdx.x * blockDim.x + threadIdx.x;  // 8,388,608 threads, 8 elems each
    const float4* xv = (const float4*)x;
    float4 v0 = xv[idx * 2];
    float4 v1 = xv[idx * 2 + 1];
    v8bf o = { (bf16)v0.x, (bf16)v0.y, (bf16)v0.z, (bf16)v0.w,
               (bf16)v1.x, (bf16)v1.y, (bf16)v1.z, (bf16)v1.w };
    *(v8bf*)(xbf + idx * 8) = o;
}

// ---------------- K0b: weights -> transposed bf16 ----------------
// Wt[c][k] = w_qkv[k][c]  (1536x512); WoT[c][k] = w_out[k][c] (512x512)
__global__ void convert_w_kernel(const float* __restrict__ wqkv, const float* __restrict__ wout,
                                 bf16* __restrict__ Wt, bf16* __restrict__ WoT) {
    int idx = blockIdx.x * 256 + threadIdx.x;        // 786,432 threads
    Wt[idx] = (bf16)wqkv[(idx & 511) * 1536 + (idx >> 9)];
    if (idx < 262144) WoT[idx] = (bf16)wout[(idx & 511) * 512 + (idx >> 9)];
}

// ---------------- K1: meta-MLP bias[h][i][j] ----------------
__global__ void bias_kernel(const float* __restrict__ rel_log, const float* __restrict__ w1,
                            const float* __restrict__ b1, const float* __restrict__ w2,
                            const float* __restrict__ b2, float* __restrict__ bias) {
    int p = blockIdx.x * 256 + threadIdx.x;          // (i,j) pair, 4096 total
    float ra = rel_log[p * 2 + 0];
    float rb = rel_log[p * 2 + 1];
    float acc[16];
    #pragma unroll
    for (int t = 0; t < 16; ++t) acc[t] = 0.f;
    for (int kk = 0; kk < 384; ++kk) {
        float hv = fmaxf(ra * w1[kk] + rb * w1[384 + kk] + b1[kk], 0.f);
        #pragma unroll
        for (int t = 0; t < 16; ++t) acc[t] += hv * w2[kk * 16 + t];
    }
    #pragma unroll
    for (int t = 0; t < 16; ++t) bias[t * 4096 + p] = acc[t] + b2[t];
}

// ---------------- K2: fused qkv GEMM + cosine attention ----------------
// grid=2048 (one batch-window), 256 thr = 4 waves, wave handles heads [4w..4w+3].
// Per-wave LDS (14848 B): q[64][40] (5120) | k[64][40] (5120) | vT[32][72] (4608);
// P[64][72] (9216) aliases q+k. All wave-private => no __syncthreads.
__global__ __launch_bounds__(256, 2) void attn_fused_kernel(
    const bf16* __restrict__ xbf,     // [131072][512]
    const bf16* __restrict__ Wt,      // [1536][512]  (qkv cols-major rows)
    const float* __restrict__ tau,    // [16]
    const float* __restrict__ bias,   // [16][64][64]
    const float* __restrict__ mask,   // [64][64][64]
    bf16* __restrict__ attn_out)      // [131072][512]
{
    __shared__ alignas(16) char smem[4 * 14848];
    const int b    = blockIdx.x;
    const int tid  = threadIdx.x;
    const int wv   = tid >> 6;
    const int lane = tid & 63;
    const int lq   = lane >> 4;   // quarter 0..3
    const int lm   = lane & 15;

    char* wb = smem + wv * 14848;
    bf16* q_lds  = (bf16*)wb;               // [64][40]
    bf16* k_lds  = (bf16*)(wb + 5120);      // [64][40]
    bf16* vT_lds = (bf16*)(wb + 10240);     // [32][72]
    bf16* P_lds  = (bf16*)wb;               // [64][72], aliases q+k

    const float* mask_w = mask + (size_t)(b & 63) * 4096;
    const v4f z4 = {0.f, 0.f, 0.f, 0.f};

    const bf16* rowA[4];
    #pragma unroll
    for (int i = 0; i < 4; ++i)
        rowA[i] = xbf + (size_t)((b * 64 + i * 16 + lm) * 512 + lq * 8);

    #pragma unroll 1
    for (int hh = 0; hh < 4; ++hh) {
        const int h = wv * 4 + hh;
        const float tau_h = tau[h];
        const bf16* rowB[6];
        #pragma unroll
        for (int j = 0; j < 6; ++j) {
            int n = (j >> 1) * 512 + h * 32 + (j & 1) * 16 + lm;
            rowB[j] = Wt + (size_t)(n * 512 + lq * 8);
        }
        // ---- qkv GEMM for this head: acc[j][i], j:0-1=q 2-3=k 4-5=v ----
        v4f acc[6][4];
        #pragma unroll
        for (int j = 0; j < 6; ++j)
            #pragma unroll
            for (int i = 0; i < 4; ++i) acc[j][i] = z4;

        #pragma unroll 2
        for (int ks = 0; ks < 16; ++ks) {
            v8bf a[4], bb[6];
            #pragma unroll
            for (int i = 0; i < 4; ++i) a[i] = *(const v8bf*)(rowA[i] + ks * 32);
            #pragma unroll
            for (int j = 0; j < 6; ++j) bb[j] = *(const v8bf*)(rowB[j] + ks * 32);
            #pragma unroll
            for (int j = 0; j < 6; ++j)
                #pragma unroll
                for (int i = 0; i < 4; ++i)
                    acc[j][i] = __builtin_amdgcn_mfma_f32_16x16x32_bf16(a[i], bb[j], acc[j][i], 0, 0, 0);
        }

        // ---- fp32 L2-normalize rows of q,k (norm over 32 dims = 2 col-tiles x 16 lanes) ----
        float scq[4][4], sck[4][4];
        #pragma unroll
        for (int i = 0; i < 4; ++i)
            #pragma unroll
            for (int r = 0; r < 4; ++r) {
                float sq = acc[0][i][r] * acc[0][i][r] + acc[1][i][r] * acc[1][i][r];
                float sk = acc[2][i][r] * acc[2][i][r] + acc[3][i][r] * acc[3][i][r];
                #pragma unroll
                for (int m = 1; m < 16; m <<= 1) {
                    sq += __shfl_xor(sq, m);
                    sk += __shfl_xor(sk, m);
                }
                scq[i][r] = tau_h / fmaxf(sqrtf(sq), 1e-12f);   // tau folded into q scale
                sck[i][r] = 1.0f / fmaxf(sqrtf(sk), 1e-12f);
            }

        // ---- write q,k (scaled) and v (transposed) to LDS ----
        #pragma unroll
        for (int i = 0; i < 4; ++i)
            #pragma unroll
            for (int r = 0; r < 4; ++r) {
                int row = i * 16 + lq * 4 + r;
                q_lds[row * 40 + lm]      = (bf16)(acc[0][i][r] * scq[i][r]);
                q_lds[row * 40 + 16 + lm] = (bf16)(acc[1][i][r] * scq[i][r]);
                k_lds[row * 40 + lm]      = (bf16)(acc[2][i][r] * sck[i][r]);
                k_lds[row * 40 + 16 + lm] = (bf16)(acc[3][i][r] * sck[i][r]);
            }
        #pragma unroll
        for (int jt = 0; jt < 2; ++jt)
            #pragma unroll
            for (int i = 0; i < 4; ++i) {
                v4bf pv = { (bf16)acc[4 + jt][i][0], (bf16)acc[4 + jt][i][1],
                            (bf16)acc[4 + jt][i][2], (bf16)acc[4 + jt][i][3] };
                int d = jt * 16 + lm;
                *(v4bf*)(vT_lds + d * 72 + i * 16 + lq * 4) = pv;   // vT[d][n], 8B packed
            }

        // ---- sim = q_n @ k_n^T (16 MFMA) ----
        v8bf qf[4], kf[4];
        #pragma unroll
        for (int i = 0; i < 4; ++i) qf[i] = *(const v8bf*)(q_lds + (i * 16 + lm) * 40 + lq * 8);
        #pragma unroll
        for (int j = 0; j < 4; ++j) kf[j] = *(const v8bf*)(k_lds + (j * 16 + lm) * 40 + lq * 8);
        v4f s[4][4];
        #pragma unroll
        for (int i = 0; i < 4; ++i)
            #pragma unroll
            for (int j = 0; j < 4; ++j)
                s[i][j] = __builtin_amdgcn_mfma_f32_16x16x32_bf16(qf[i], kf[j], z4, 0, 0, 0);

        // ---- + bias[h] + mask[w], softmax over keys (cols) ----
        const float* bias_h = bias + (size_t)h * 4096;
        #pragma unroll
        for (int i = 0; i < 4; ++i)
            #pragma unroll
            for (int j = 0; j < 4; ++j)
                #pragma unroll
                for (int r = 0; r < 4; ++r) {
                    int row = i * 16 + lq * 4 + r, col = j * 16 + lm;
                    s[i][j][r] += bias_h[row * 64 + col] + mask_w[row * 64 + col];
                }
        float rcpl[4][4];
        #pragma unroll
        for (int i = 0; i < 4; ++i) {
            float mx[4], sm[4];
            #pragma unroll
            for (int r = 0; r < 4; ++r) {
                mx[r] = fmaxf(fmaxf(s[i][0][r], s[i][1][r]), fmaxf(s[i][2][r], s[i][3][r]));
                #pragma unroll
                for (int m = 1; m < 16; m <<= 1) mx[r] = fmaxf(mx[r], __shfl_xor(mx[r], m));
                sm[r] = 0.f;
            }
            #pragma unroll
            for (int j = 0; j < 4; ++j)
                #pragma unroll
                for (int r = 0; r < 4; ++r) {
                    s[i][j][r] = __expf(s[i][j][r] - mx[r]);
                    sm[r] += s[i][j][r];
                }
            #pragma unroll
            for (int r = 0; r < 4; ++r) {
                #pragma unroll
                for (int m = 1; m < 16; m <<= 1) sm[r] += __shfl_xor(sm[r], m);
                rcpl[i][r] = 1.0f / sm[r];
            }
        }

        // ---- P -> LDS (aliases q/k region; q/k frags already consumed) ----
        #pragma unroll
        for (int i = 0; i < 4; ++i)
            #pragma unroll
            for (int j = 0; j < 4; ++j)
                #pragma unroll
                for (int r = 0; r < 4; ++r)
                    P_lds[(i * 16 + lq * 4 + r) * 72 + j * 16 + lm] = (bf16)s[i][j][r];

        // ---- out = (P @ V) * rcpl  (16 MFMA, K=64 in 2 steps) ----
        v4f o[4][2];
        #pragma unroll
        for (int i = 0; i < 4; ++i)
            #pragma unroll
            for (int nt = 0; nt < 2; ++nt) o[i][nt] = z4;
        #pragma unroll
        for (int kk = 0; kk < 2; ++kk) {
            v8bf vf[2], pf[4];
            #pragma unroll
            for (int nt = 0; nt < 2; ++nt)
                vf[nt] = *(const v8bf*)(vT_lds + (nt * 16 + lm) * 72 + kk * 32 + lq * 8);
            #pragma unroll
            for (int i = 0; i < 4; ++i)
                pf[i] = *(const v8bf*)(P_lds + (i * 16 + lm) * 72 + kk * 32 + lq * 8);
            #pragma unroll
            for (int i = 0; i < 4; ++i)
                #pragma unroll
                for (int nt = 0; nt < 2; ++nt)
                    o[i][nt] = __builtin_amdgcn_mfma_f32_16x16x32_bf16(pf[i], vf[nt], o[i][nt], 0, 0, 0);
        }
        #pragma unroll
        for (int i = 0; i < 4; ++i)
            #pragma unroll
            for (int nt = 0; nt < 2; ++nt)
                #pragma unroll
                for (int r = 0; r < 4; ++r)
                    attn_out[(size_t)(b * 64 + i * 16 + lq * 4 + r) * 512 + h * 32 + nt * 16 + lm] =
                        (bf16)(o[i][nt][r] * rcpl[i][r]);
    }
}

// ---------------- K3: out-projection GEMM, m97-style 128x128, BK=32 ----------------
__global__ __launch_bounds__(256) void proj_gemm_kernel(
    const bf16* __restrict__ A,     // [131072][512] attn_out
    const bf16* __restrict__ Bt,    // [512][512] WoT (out-col major rows)
    const float* __restrict__ b_out,
    float* __restrict__ out)        // [131072][512]
{
    __shared__ alignas(16) bf16 Alds[128 * 32];
    __shared__ alignas(16) bf16 Blds[128 * 32];
    const int mb = blockIdx.x, nb = blockIdx.y;
    const int tid = threadIdx.x;
    const int wv = tid >> 6, lane = tid & 63, lq = lane >> 4, lm = lane & 15;
    const int wr = wv >> 1, wc = wv & 1;      // wave 64x64 sub-tile

    v4f acc[4][4];
    #pragma unroll
    for (int i = 0; i < 4; ++i)
        #pragma unroll
        for (int j = 0; j < 4; ++j) acc[i][j] = v4f{0.f, 0.f, 0.f, 0.f};

    const char* aBase = (const char*)A + (size_t)mb * 128 * 1024;
    const char* bBase = (const char*)Bt + (size_t)nb * 128 * 1024;

    for (int kt = 0; kt < 16; ++kt) {
        __syncthreads();
        #pragma unroll
        for (int p = 0; p < 2; ++p) {
            int idx = (p * 4 + wv) * 1024 + lane * 16;   // byte index into 8KB tile
            int row = idx >> 6, kb = idx & 63;
            __builtin_amdgcn_global_load_lds(
                (const __attribute__((address_space(1))) void*)(aBase + (size_t)row * 1024 + kt * 64 + kb),
                (__attribute__((address_space(3))) void*)((char*)Alds + (p * 4 + wv) * 1024),
                16, 0, 0);
            __builtin_amdgcn_global_load_lds(
                (const __attribute__((address_space(1))) void*)(bBase + (size_t)row * 1024 + kt * 64 + kb),
                (__attribute__((address_space(3))) void*)((char*)Blds + (p * 4 + wv) * 1024),
                16, 0, 0);
        }
        __syncthreads();
        v8bf af[4], bfj[4];
        #pragma unroll
        for (int i = 0; i < 4; ++i)
            af[i] = *(const v8bf*)(Alds + (wr * 64 + i * 16 + lm) * 32 + lq * 8);
        #pragma unroll
        for (int j = 0; j < 4; ++j)
            bfj[j] = *(const v8bf*)(Blds + (wc * 64 + j * 16 + lm) * 32 + lq * 8);
        #pragma unroll
        for (int i = 0; i < 4; ++i)
            #pragma unroll
            for (int j = 0; j < 4; ++j)
                acc[i][j] = __builtin_amdgcn_mfma_f32_16x16x32_bf16(af[i], bfj[j], acc[i][j], 0, 0, 0);
    }

    #pragma unroll
    for (int j = 0; j < 4; ++j) {
        int col = nb * 128 + wc * 64 + j * 16 + lm;
        float bo = b_out[col];
        #pragma unroll
        for (int i = 0; i < 4; ++i)
            #pragma unroll
            for (int r = 0; r < 4; ++r)
                out[(size_t)(mb * 128 + wr * 64 + i * 16 + lq * 4 + r) * 512 + col] = acc[i][j][r] + bo;
    }
}

// ---------------- launch ----------------
extern "C" void kernel_launch(void* const* d_in, const int* in_sizes, int n_in,
                              void* d_out, int out_size, void* d_ws, size_t ws_size,
                              hipStream_t stream) {
    (void)in_sizes; (void)n_in; (void)out_size; (void)ws_size;
    const float* x       = (const float*)d_in[0];
    const float* mask    = (const float*)d_in[1];
    const float* w_qkv   = (const float*)d_in[2];
    const float* tau     = (const float*)d_in[3];
    const float* mlp_w1  = (const float*)d_in[4];
    const float* mlp_b1  = (const float*)d_in[5];
    const float* mlp_w2  = (const float*)d_in[6];
    const float* mlp_b2  = (const float*)d_in[7];
    const float* w_out   = (const float*)d_in[8];
    const float* b_out   = (const float*)d_in[9];
    const float* rel_log = (const float*)d_in[10];
    float* out = (float*)d_out;

    char* ws = (char*)d_ws;
    bf16*  Wt       = (bf16*)(ws);                         // 1,572,864 B
    bf16*  WoT      = (bf16*)(ws + 1572864);               //   524,288 B
    float* bias     = (float*)(ws + 2097152);              //   262,144 B
    bf16*  xbf      = (bf16*)(ws + 2359296);               // 134,217,728 B
    bf16*  attn_out = (bf16*)(ws + 2359296 + 134217728);   // 134,217,728 B  (total ~271 MB)

    convert_x_kernel<<<32768, 256, 0, stream>>>(x, xbf);
    convert_w_kernel<<<3072, 256, 0, stream>>>(w_qkv, w_out, Wt, WoT);
    bias_kernel<<<16, 256, 0, stream>>>(rel_log, mlp_w1, mlp_b1, mlp_w2, mlp_b2, bias);
    attn_fused_kernel<<<2048, 256, 0, stream>>>(xbf, Wt, tau, bias, mask, attn_out);
    proj_gemm_kernel<<<dim3(1024, 4), 256, 0, stream>>>(attn_out, WoT, b_out, out);
}

// Round 3
// 1019.566 us; speedup vs baseline: 1.2869x; 1.2869x over previous
//
#include <hip/hip_runtime.h>
#include <hip/hip_bf16.h>

// WindowAttentionV2: B_NW=2048, N=64, DIM=512, NH=16, DH=32, HID=384, NW=64
// v2 pipeline: convert_w + bias MLP -> per chunk { qkv GEMM (+norm epilogue) -> lean attn } -> proj GEMM.

typedef __bf16 bf16;
typedef __bf16 v4bf __attribute__((ext_vector_type(4)));
typedef __bf16 v8bf __attribute__((ext_vector_type(8)));
typedef float  v4f  __attribute__((ext_vector_type(4)));

// ---------------- K0: weights -> transposed bf16 ----------------
// Wt[c][k] = w_qkv[k][c]  (1536x512); WoT[c][k] = w_out[k][c] (512x512)
__global__ void convert_w_kernel(const float* __restrict__ wqkv, const float* __restrict__ wout,
                                 bf16* __restrict__ Wt, bf16* __restrict__ WoT) {
    int idx = blockIdx.x * 256 + threadIdx.x;        // 786,432 threads
    Wt[idx] = (bf16)wqkv[(idx & 511) * 1536 + (idx >> 9)];
    if (idx < 262144) WoT[idx] = (bf16)wout[(idx & 511) * 512 + (idx >> 9)];
}

// ---------------- K1: meta-MLP bias[h][i][j] ----------------
__global__ void bias_kernel(const float* __restrict__ rel_log, const float* __restrict__ w1,
                            const float* __restrict__ b1, const float* __restrict__ w2,
                            const float* __restrict__ b2, float* __restrict__ bias) {
    int p = blockIdx.x * 256 + threadIdx.x;          // (i,j) pair, 4096 total
    float ra = rel_log[p * 2 + 0];
    float rb = rel_log[p * 2 + 1];
    float acc[16];
    #pragma unroll
    for (int t = 0; t < 16; ++t) acc[t] = 0.f;
    for (int kk = 0; kk < 384; ++kk) {
        float hv = fmaxf(ra * w1[kk] + rb * w1[384 + kk] + b1[kk], 0.f);
        #pragma unroll
        for (int t = 0; t < 16; ++t) acc[t] += hv * w2[kk * 16 + t];
    }
    #pragma unroll
    for (int t = 0; t < 16; ++t) bias[t * 4096 + p] = acc[t] + b2[t];
}

// ---------------- K2: qkv GEMM (fp32 A converted in staging) + cosine-norm epilogue ----------------
// Tile 128x128, BK=32, 4 waves (each 64x64). Grid 1D = 6*W blocks, nb (0..11) fastest after XCD swizzle.
// Outputs (chunk-local, W windows): q_ws/k_ws [bw*16+h][n(64)][dh(32)] bf16 (q scaled tau/||q||, k by 1/||k||),
// v_ws [bw*16+h][dh(32)][n(64)] bf16 (transposed for PV B-frags).
__global__ __launch_bounds__(256, 3) void qkv_gemm_kernel(
    const float* __restrict__ x,    // [Mc][512] chunk rows
    const bf16* __restrict__ Wt,    // [1536][512]
    const float* __restrict__ tau,  // [16]
    bf16* __restrict__ q_ws, bf16* __restrict__ k_ws, bf16* __restrict__ v_ws)
{
    __shared__ alignas(16) bf16 Alds[128 * 40];   // padded stride 40 elems (80B)
    __shared__ alignas(16) bf16 Blds[128 * 40];
    const int bid = blockIdx.x, nwg = gridDim.x;
    const int wid = (bid & 7) * (nwg >> 3) + (bid >> 3);   // XCD-bijective swizzle (nwg%8==0)
    const int nb = wid % 12, mb = wid / 12;

    const int t = threadIdx.x;
    const int wv = t >> 6, lane = t & 63, lq = lane >> 4, lm = lane & 15;
    const int wr = wv >> 1, wc = wv & 1;
    const int srow = t >> 1, sseg = (t & 1) * 16;

    const float* aptr = x + (size_t)(mb * 128 + srow) * 512 + sseg;
    const bf16*  bptr = Wt + (size_t)(nb * 128 + srow) * 512 + sseg;
    bf16* awp = Alds + srow * 40 + sseg;
    bf16* bwp = Blds + srow * 40 + sseg;

    v4f acc[4][4];
    #pragma unroll
    for (int i = 0; i < 4; ++i)
        #pragma unroll
        for (int j = 0; j < 4; ++j) acc[i][j] = v4f{0.f, 0.f, 0.f, 0.f};

    for (int kt = 0; kt < 16; ++kt) {
        // issue global loads before the barrier: overlaps previous step's MFMA
        float4 f0 = *(const float4*)(aptr + kt * 32);
        float4 f1 = *(const float4*)(aptr + kt * 32 + 4);
        float4 f2 = *(const float4*)(aptr + kt * 32 + 8);
        float4 f3 = *(const float4*)(aptr + kt * 32 + 12);
        v8bf bv0 = *(const v8bf*)(bptr + kt * 32);
        v8bf bv1 = *(const v8bf*)(bptr + kt * 32 + 8);
        __syncthreads();   // previous step's frag reads complete
        v8bf a0 = { (bf16)f0.x, (bf16)f0.y, (bf16)f0.z, (bf16)f0.w,
                    (bf16)f1.x, (bf16)f1.y, (bf16)f1.z, (bf16)f1.w };
        v8bf a1 = { (bf16)f2.x, (bf16)f2.y, (bf16)f2.z, (bf16)f2.w,
                    (bf16)f3.x, (bf16)f3.y, (bf16)f3.z, (bf16)f3.w };
        *(v8bf*)awp = a0;  *(v8bf*)(awp + 8) = a1;
        *(v8bf*)bwp = bv0; *(v8bf*)(bwp + 8) = bv1;
        __syncthreads();
        v8bf af[4], bfj[4];
        #pragma unroll
        for (int i = 0; i < 4; ++i)
            af[i] = *(const v8bf*)(Alds + (wr * 64 + i * 16 + lm) * 40 + lq * 8);
        #pragma unroll
        for (int j = 0; j < 4; ++j)
            bfj[j] = *(const v8bf*)(Blds + (wc * 64 + j * 16 + lm) * 40 + lq * 8);
        #pragma unroll
        for (int i = 0; i < 4; ++i)
            #pragma unroll
            for (int j = 0; j < 4; ++j)
                acc[i][j] = __builtin_amdgcn_mfma_f32_16x16x32_bf16(af[i], bfj[j], acc[i][j], 0, 0, 0);
    }

    // epilogue: row = mb*128 + wr*64 + i*16 + lq*4 + r (window bw = mb*2+wr, n = i*16+lq*4+r)
    // col = nb*128 + wc*64 + j*16 + lm; q: nb<4, k: nb<8, v: else
    const int bw = mb * 2 + wr;
    if (nb < 8) {
        bf16* dst = (nb < 4) ? q_ws : k_ws;
        const int hbase = (nb & 3) * 4 + wc * 2;
        #pragma unroll
        for (int tpair = 0; tpair < 2; ++tpair) {
            const int h = hbase + tpair;
            const float sc_top = (nb < 4) ? tau[h] : 1.0f;
            #pragma unroll
            for (int i = 0; i < 4; ++i)
                #pragma unroll
                for (int r = 0; r < 4; ++r) {
                    float a0 = acc[i][2 * tpair][r], a1 = acc[i][2 * tpair + 1][r];
                    float ss = a0 * a0 + a1 * a1;
                    #pragma unroll
                    for (int m = 1; m < 16; m <<= 1) ss += __shfl_xor(ss, m);
                    float sc = sc_top / fmaxf(sqrtf(ss), 1e-12f);
                    int n = i * 16 + lq * 4 + r;
                    size_t base = ((size_t)(bw * 16 + h) * 64 + n) * 32;
                    dst[base + lm]      = (bf16)(a0 * sc);
                    dst[base + 16 + lm] = (bf16)(a1 * sc);
                }
        }
    } else {
        #pragma unroll
        for (int j = 0; j < 4; ++j) {
            const int h = (nb - 8) * 4 + wc * 2 + (j >> 1);
            const int dh = (j & 1) * 16 + lm;
            #pragma unroll
            for (int i = 0; i < 4; ++i) {
                v4bf pv = { (bf16)acc[i][j][0], (bf16)acc[i][j][1],
                            (bf16)acc[i][j][2], (bf16)acc[i][j][3] };
                *(v4bf*)(v_ws + ((size_t)(bw * 16 + h) * 32 + dh) * 64 + i * 16 + lq * 4) = pv;
            }
        }
    }
}

// ---------------- K3: lean attention ----------------
// grid = W windows, 256 thr = 4 waves; wave wv handles heads 4wv..4wv+3 sequentially.
// LDS: mask (16KB, staged once) + per-wave P [64][72] bf16.
__global__ __launch_bounds__(256, 3) void attn_kernel(
    const bf16* __restrict__ q_ws,   // [bw*16+h][64][32]
    const bf16* __restrict__ k_ws,
    const bf16* __restrict__ v_ws,   // [bw*16+h][32][64]
    const float* __restrict__ bias,  // [16][4096]
    const float* __restrict__ mask,  // [64][4096]
    bf16* __restrict__ attn_out)     // chunk-offset applied by caller, [rows][512]
{
    __shared__ float mask_lds[4096];
    __shared__ alignas(16) bf16 P_all[4][64 * 72];
    const int b = blockIdx.x;
    const int tid = threadIdx.x;
    const int wv = tid >> 6, lane = tid & 63, lq = lane >> 4, lm = lane & 15;
    const v4f z4 = {0.f, 0.f, 0.f, 0.f};

    {
        const float4* ms = (const float4*)(mask + (size_t)(b & 63) * 4096);
        float4* md = (float4*)mask_lds;
        #pragma unroll
        for (int r = 0; r < 4; ++r) md[tid + r * 256] = ms[tid + r * 256];
    }
    __syncthreads();

    bf16* P = P_all[wv];

    #pragma unroll 1
    for (int hh = 0; hh < 4; ++hh) {
        const int h = wv * 4 + hh;
        const size_t qk_base = (size_t)(b * 16 + h) * 64 * 32;

        v8bf qf[4], kf[4];
        #pragma unroll
        for (int i = 0; i < 4; ++i)
            qf[i] = *(const v8bf*)(q_ws + qk_base + (i * 16 + lm) * 32 + lq * 8);
        #pragma unroll
        for (int j = 0; j < 4; ++j)
            kf[j] = *(const v8bf*)(k_ws + qk_base + (j * 16 + lm) * 32 + lq * 8);

        v4f s[4][4];
        #pragma unroll
        for (int i = 0; i < 4; ++i)
            #pragma unroll
            for (int j = 0; j < 4; ++j)
                s[i][j] = __builtin_amdgcn_mfma_f32_16x16x32_bf16(qf[i], kf[j], z4, 0, 0, 0);

        const float* bias_h = bias + (size_t)h * 4096;
        #pragma unroll
        for (int i = 0; i < 4; ++i)
            #pragma unroll
            for (int j = 0; j < 4; ++j)
                #pragma unroll
                for (int r = 0; r < 4; ++r) {
                    int idx = (i * 16 + lq * 4 + r) * 64 + j * 16 + lm;
                    s[i][j][r] += bias_h[idx] + mask_lds[idx];
                }

        float rcpl[4][4];
        #pragma unroll
        for (int i = 0; i < 4; ++i) {
            float mx[4], sm[4];
            #pragma unroll
            for (int r = 0; r < 4; ++r) {
                mx[r] = fmaxf(fmaxf(s[i][0][r], s[i][1][r]), fmaxf(s[i][2][r], s[i][3][r]));
                #pragma unroll
                for (int m = 1; m < 16; m <<= 1) mx[r] = fmaxf(mx[r], __shfl_xor(mx[r], m));
                sm[r] = 0.f;
            }
            #pragma unroll
            for (int j = 0; j < 4; ++j)
                #pragma unroll
                for (int r = 0; r < 4; ++r) {
                    s[i][j][r] = __expf(s[i][j][r] - mx[r]);
                    sm[r] += s[i][j][r];
                }
            #pragma unroll
            for (int r = 0; r < 4; ++r) {
                #pragma unroll
                for (int m = 1; m < 16; m <<= 1) sm[r] += __shfl_xor(sm[r], m);
                rcpl[i][r] = 1.0f / sm[r];
            }
        }

        // P -> LDS (wave-private; same-wave ds ordering handled by waitcnt)
        #pragma unroll
        for (int i = 0; i < 4; ++i)
            #pragma unroll
            for (int j = 0; j < 4; ++j)
                #pragma unroll
                for (int r = 0; r < 4; ++r)
                    P[(i * 16 + lq * 4 + r) * 72 + j * 16 + lm] = (bf16)s[i][j][r];

        const size_t v_base = (size_t)(b * 16 + h) * 32 * 64;
        v4f o[4][2];
        #pragma unroll
        for (int i = 0; i < 4; ++i)
            #pragma unroll
            for (int nt = 0; nt < 2; ++nt) o[i][nt] = z4;
        #pragma unroll
        for (int kk = 0; kk < 2; ++kk) {
            v8bf vf[2], pf[4];
            #pragma unroll
            for (int nt = 0; nt < 2; ++nt)
                vf[nt] = *(const v8bf*)(v_ws + v_base + (nt * 16 + lm) * 64 + kk * 32 + lq * 8);
            #pragma unroll
            for (int i = 0; i < 4; ++i)
                pf[i] = *(const v8bf*)(P + (i * 16 + lm) * 72 + kk * 32 + lq * 8);
            #pragma unroll
            for (int i = 0; i < 4; ++i)
                #pragma unroll
                for (int nt = 0; nt < 2; ++nt)
                    o[i][nt] = __builtin_amdgcn_mfma_f32_16x16x32_bf16(pf[i], vf[nt], o[i][nt], 0, 0, 0);
        }
        #pragma unroll
        for (int i = 0; i < 4; ++i)
            #pragma unroll
            for (int nt = 0; nt < 2; ++nt)
                #pragma unroll
                for (int r = 0; r < 4; ++r)
                    attn_out[(size_t)(b * 64 + i * 16 + lq * 4 + r) * 512 + h * 32 + nt * 16 + lm] =
                        (bf16)(o[i][nt][r] * rcpl[i][r]);
    }
}

// ---------------- K4: out-projection GEMM, 128x128, BK=32, global_load_lds ----------------
__global__ __launch_bounds__(256) void proj_gemm_kernel(
    const bf16* __restrict__ A,     // [131072][512] attn_out
    const bf16* __restrict__ Bt,    // [512][512] WoT
    const float* __restrict__ b_out,
    float* __restrict__ out)        // [131072][512]
{
    __shared__ alignas(16) bf16 Alds[128 * 32];
    __shared__ alignas(16) bf16 Blds[128 * 32];
    const int bid = blockIdx.x;                       // 4096 blocks
    const int wid = (bid & 7) * 512 + (bid >> 3);     // XCD swizzle
    const int mb = wid >> 2, nb = wid & 3;            // nb fastest: A-tile reuse within XCD
    const int tid = threadIdx.x;
    const int wv = tid >> 6, lane = tid & 63, lq = lane >> 4, lm = lane & 15;
    const int wr = wv >> 1, wc = wv & 1;

    v4f acc[4][4];
    #pragma unroll
    for (int i = 0; i < 4; ++i)
        #pragma unroll
        for (int j = 0; j < 4; ++j) acc[i][j] = v4f{0.f, 0.f, 0.f, 0.f};

    const char* aBase = (const char*)A + (size_t)mb * 128 * 1024;
    const char* bBase = (const char*)Bt + (size_t)nb * 128 * 1024;

    for (int kt = 0; kt < 16; ++kt) {
        __syncthreads();
        #pragma unroll
        for (int p = 0; p < 2; ++p) {
            int idx = (p * 4 + wv) * 1024 + lane * 16;
            int row = idx >> 6, kb = idx & 63;
            __builtin_amdgcn_global_load_lds(
                (const __attribute__((address_space(1))) void*)(aBase + (size_t)row * 1024 + kt * 64 + kb),
                (__attribute__((address_space(3))) void*)((char*)Alds + (p * 4 + wv) * 1024),
                16, 0, 0);
            __builtin_amdgcn_global_load_lds(
                (const __attribute__((address_space(1))) void*)(bBase + (size_t)row * 1024 + kt * 64 + kb),
                (__attribute__((address_space(3))) void*)((char*)Blds + (p * 4 + wv) * 1024),
                16, 0, 0);
        }
        __syncthreads();
        v8bf af[4], bfj[4];
        #pragma unroll
        for (int i = 0; i < 4; ++i)
            af[i] = *(const v8bf*)(Alds + (wr * 64 + i * 16 + lm) * 32 + lq * 8);
        #pragma unroll
        for (int j = 0; j < 4; ++j)
            bfj[j] = *(const v8bf*)(Blds + (wc * 64 + j * 16 + lm) * 32 + lq * 8);
        #pragma unroll
        for (int i = 0; i < 4; ++i)
            #pragma unroll
            for (int j = 0; j < 4; ++j)
                acc[i][j] = __builtin_amdgcn_mfma_f32_16x16x32_bf16(af[i], bfj[j], acc[i][j], 0, 0, 0);
    }

    #pragma unroll
    for (int j = 0; j < 4; ++j) {
        int col = nb * 128 + wc * 64 + j * 16 + lm;
        float bo = b_out[col];
        #pragma unroll
        for (int i = 0; i < 4; ++i)
            #pragma unroll
            for (int r = 0; r < 4; ++r)
                out[(size_t)(mb * 128 + wr * 64 + i * 16 + lq * 4 + r) * 512 + col] = acc[i][j][r] + bo;
    }
}

// ---------------- launch ----------------
extern "C" void kernel_launch(void* const* d_in, const int* in_sizes, int n_in,
                              void* d_out, int out_size, void* d_ws, size_t ws_size,
                              hipStream_t stream) {
    (void)in_sizes; (void)n_in; (void)out_size;
    const float* x       = (const float*)d_in[0];
    const float* mask    = (const float*)d_in[1];
    const float* w_qkv   = (const float*)d_in[2];
    const float* tau     = (const float*)d_in[3];
    const float* mlp_w1  = (const float*)d_in[4];
    const float* mlp_b1  = (const float*)d_in[5];
    const float* mlp_w2  = (const float*)d_in[6];
    const float* mlp_b2  = (const float*)d_in[7];
    const float* w_out   = (const float*)d_in[8];
    const float* b_out   = (const float*)d_in[9];
    const float* rel_log = (const float*)d_in[10];
    float* out = (float*)d_out;

    char* ws = (char*)d_ws;
    bf16*  Wt       = (bf16*)(ws);                       // 1,572,864 B
    bf16*  WoT      = (bf16*)(ws + 1572864);             //   524,288 B
    float* bias     = (float*)(ws + 2097152);            //   262,144 B
    bf16*  attn_out = (bf16*)(ws + 2359296);             // 134,217,728 B
    char*  qkv_base = ws + 2359296 + 134217728;          // 136,577,024 fixed

    // chunking: W windows/chunk; qkv chunk buffers = W*196608 B (stays L3-resident)
    size_t avail = (ws_size > 136577024ULL) ? ws_size - 136577024ULL : 0;
    int W = 2048;
    while (W > 256 && (size_t)W * 196608ULL > avail) W >>= 1;
    const size_t qkbuf = (size_t)W * 65536;              // q/k/v each
    bf16* qb = (bf16*)qkv_base;
    bf16* kb = (bf16*)(qkv_base + qkbuf);
    bf16* vb = (bf16*)(qkv_base + 2 * qkbuf);

    convert_w_kernel<<<3072, 256, 0, stream>>>(w_qkv, w_out, Wt, WoT);
    bias_kernel<<<16, 256, 0, stream>>>(rel_log, mlp_w1, mlp_b1, mlp_w2, mlp_b2, bias);

    const int nchunk = 2048 / W;
    for (int c = 0; c < nchunk; ++c) {
        const float* xc = x + (size_t)c * W * 64 * 512;
        bf16* aoc = attn_out + (size_t)c * W * 64 * 512;
        qkv_gemm_kernel<<<6 * W, 256, 0, stream>>>(xc, Wt, tau, qb, kb, vb);
        attn_kernel<<<W, 256, 0, stream>>>(qb, kb, vb, bias, mask, aoc);
    }
    proj_gemm_kernel<<<4096, 256, 0, stream>>>(attn_out, WoT, b_out, out);
}

// Round 5
// 886.730 us; speedup vs baseline: 1.4797x; 1.1498x over previous
//
#include <hip/hip_runtime.h>
#include <hip/hip_bf16.h>

// WindowAttentionV2: B_NW=2048, N=64, DIM=512, NH=16, DH=32, HID=384, NW=64
// v4: convert_w + bias + comb + convert_x -> per chunk { qkv GEMM (m97) -> attn } -> proj.
// xbf and attn_out SHARE one 134MB buffer (chunk slice flips producer after qkv reads it).

typedef __bf16 bf16;
typedef __bf16 v4bf __attribute__((ext_vector_type(4)));
typedef __bf16 v8bf __attribute__((ext_vector_type(8)));
typedef float  v4f  __attribute__((ext_vector_type(4)));

// ---------------- K0a: x fp32 -> bf16 (grid-stride) ----------------
__global__ void convert_x_kernel(const float* __restrict__ x, bf16* __restrict__ xbf) {
    const int stride = gridDim.x * 256;
    for (size_t idx = blockIdx.x * 256 + threadIdx.x; idx < 8388608; idx += stride) {
        const float4* xv = (const float4*)x;
        float4 v0 = xv[idx * 2];
        float4 v1 = xv[idx * 2 + 1];
        v8bf o = { (bf16)v0.x, (bf16)v0.y, (bf16)v0.z, (bf16)v0.w,
                   (bf16)v1.x, (bf16)v1.y, (bf16)v1.z, (bf16)v1.w };
        *(v8bf*)(xbf + idx * 8) = o;
    }
}

// ---------------- K0b: weights -> transposed bf16 ----------------
__global__ void convert_w_kernel(const float* __restrict__ wqkv, const float* __restrict__ wout,
                                 bf16* __restrict__ Wt, bf16* __restrict__ WoT) {
    int idx = blockIdx.x * 256 + threadIdx.x;        // 786,432 threads
    Wt[idx] = (bf16)wqkv[(idx & 511) * 1536 + (idx >> 9)];
    if (idx < 262144) WoT[idx] = (bf16)wout[(idx & 511) * 512 + (idx >> 9)];
}

// ---------------- K1a: meta-MLP bias[h][i][j] ----------------
__global__ void bias_kernel(const float* __restrict__ rel_log, const float* __restrict__ w1,
                            const float* __restrict__ b1, const float* __restrict__ w2,
                            const float* __restrict__ b2, float* __restrict__ bias) {
    int p = blockIdx.x * 256 + threadIdx.x;          // (i,j) pair, 4096 total
    float ra = rel_log[p * 2 + 0];
    float rb = rel_log[p * 2 + 1];
    float acc[16];
    #pragma unroll
    for (int t = 0; t < 16; ++t) acc[t] = 0.f;
    for (int kk = 0; kk < 384; ++kk) {
        float hv = fmaxf(ra * w1[kk] + rb * w1[384 + kk] + b1[kk], 0.f);
        #pragma unroll
        for (int t = 0; t < 16; ++t) acc[t] += hv * w2[kk * 16 + t];
    }
    #pragma unroll
    for (int t = 0; t < 16; ++t) bias[t * 4096 + p] = acc[t] + b2[t];
}

// ---------------- K1b: comb[w][h][p] = bias[h][p] + mask[w][p] (float4) ----------------
__global__ void comb_kernel(const float* __restrict__ bias, const float* __restrict__ mask,
                            float* __restrict__ comb) {
    int g4 = blockIdx.x * 256 + threadIdx.x;         // 1,048,576 float4 groups
    int g = g4 * 4;
    int w = g >> 16, h = (g >> 12) & 15, p = g & 4095;
    float4 bv = *(const float4*)(bias + h * 4096 + p);
    float4 mv = *(const float4*)(mask + w * 4096 + p);
    *(float4*)(comb + g) = float4{bv.x + mv.x, bv.y + mv.y, bv.z + mv.z, bv.w + mv.w};
}

// ---------------- K2: qkv GEMM (m97: BK=32, global_load_lds w16) + cosine-norm epilogue ----------------
// Tile 128x128, 4 waves (64x64 each). Grid 6*W blocks (W/2 m-tiles x 12 nb); nb fastest after swizzle.
// Outputs: q_ws/k_ws [bw*16+h][n(64)][dh(32)] bf16 (q scaled tau/||q||, k by 1/||k||),
// v_ws [bw*16+h][dh(32)][n(64)] bf16 (transposed for PV B-frags).
__global__ __launch_bounds__(256) void qkv_gemm_kernel(
    const bf16* __restrict__ xbf,   // [Mc][512] chunk rows, bf16
    const bf16* __restrict__ Wt,    // [1536][512]
    const float* __restrict__ tau,  // [16]
    bf16* __restrict__ q_ws, bf16* __restrict__ k_ws, bf16* __restrict__ v_ws)
{
    __shared__ alignas(16) bf16 Alds[128 * 32];
    __shared__ alignas(16) bf16 Blds[128 * 32];
    const int bid = blockIdx.x, nwg = gridDim.x;
    const int wid = (bid & 7) * (nwg >> 3) + (bid >> 3);   // XCD-bijective (nwg%8==0)
    const int nb = wid % 12, mb = wid / 12;                // mb in [0, W/2)

    const int t = threadIdx.x;
    const int wv = t >> 6, lane = t & 63, lq = lane >> 4, lm = lane & 15;
    const int wr = wv >> 1, wc = wv & 1;

    const char* aBase = (const char*)xbf + (size_t)mb * 128 * 1024;
    const char* bBase = (const char*)Wt + (size_t)nb * 128 * 1024;

    v4f acc[4][4];
    #pragma unroll
    for (int i = 0; i < 4; ++i)
        #pragma unroll
        for (int j = 0; j < 4; ++j) acc[i][j] = v4f{0.f, 0.f, 0.f, 0.f};

    for (int kt = 0; kt < 16; ++kt) {
        __syncthreads();
        #pragma unroll
        for (int p = 0; p < 2; ++p) {
            int idx = (p * 4 + wv) * 1024 + lane * 16;     // byte offset in 8KB tile
            int row = idx >> 6, kb = idx & 63;
            __builtin_amdgcn_global_load_lds(
                (const __attribute__((address_space(1))) void*)(aBase + (size_t)row * 1024 + kt * 64 + kb),
                (__attribute__((address_space(3))) void*)((char*)Alds + (p * 4 + wv) * 1024),
                16, 0, 0);
            __builtin_amdgcn_global_load_lds(
                (const __attribute__((address_space(1))) void*)(bBase + (size_t)row * 1024 + kt * 64 + kb),
                (__attribute__((address_space(3))) void*)((char*)Blds + (p * 4 + wv) * 1024),
                16, 0, 0);
        }
        __syncthreads();
        v8bf af[4], bfj[4];
        #pragma unroll
        for (int i = 0; i < 4; ++i)
            af[i] = *(const v8bf*)(Alds + (wr * 64 + i * 16 + lm) * 32 + lq * 8);
        #pragma unroll
        for (int j = 0; j < 4; ++j)
            bfj[j] = *(const v8bf*)(Blds + (wc * 64 + j * 16 + lm) * 32 + lq * 8);
        #pragma unroll
        for (int i = 0; i < 4; ++i)
            #pragma unroll
            for (int j = 0; j < 4; ++j)
                acc[i][j] = __builtin_amdgcn_mfma_f32_16x16x32_bf16(af[i], bfj[j], acc[i][j], 0, 0, 0);
    }

    // epilogue: row = mb*128 + wr*64 + i*16 + lq*4 + r (window bw=mb*2+wr, n=i*16+lq*4+r)
    // col = nb*128 + wc*64 + j*16 + lm; nb<4: q, nb<8: k, else v
    const int bw = mb * 2 + wr;
    if (nb < 8) {
        bf16* dst = (nb < 4) ? q_ws : k_ws;
        const int hbase = (nb & 3) * 4 + wc * 2;
        #pragma unroll
        for (int tpair = 0; tpair < 2; ++tpair) {
            const int h = hbase + tpair;
            const float sc_top = (nb < 4) ? tau[h] : 1.0f;
            #pragma unroll
            for (int i = 0; i < 4; ++i)
                #pragma unroll
                for (int r = 0; r < 4; ++r) {
                    float a0 = acc[i][2 * tpair][r], a1 = acc[i][2 * tpair + 1][r];
                    float ss = a0 * a0 + a1 * a1;
                    #pragma unroll
                    for (int m = 1; m < 16; m <<= 1) ss += __shfl_xor(ss, m);
                    float sc = sc_top / fmaxf(sqrtf(ss), 1e-12f);
                    int n = i * 16 + lq * 4 + r;
                    size_t base = ((size_t)(bw * 16 + h) * 64 + n) * 32;
                    dst[base + lm]      = (bf16)(a0 * sc);
                    dst[base + 16 + lm] = (bf16)(a1 * sc);
                }
        }
    } else {
        #pragma unroll
        for (int j = 0; j < 4; ++j) {
            const int h = (nb - 8) * 4 + wc * 2 + (j >> 1);
            const int dh = (j & 1) * 16 + lm;
            #pragma unroll
            for (int i = 0; i < 4; ++i) {
                v4bf pv = { (bf16)acc[i][j][0], (bf16)acc[i][j][1],
                            (bf16)acc[i][j][2], (bf16)acc[i][j][3] };
                *(v4bf*)(v_ws + ((size_t)(bw * 16 + h) * 32 + dh) * 64 + i * 16 + lq * 4) = pv;
            }
        }
    }
}

// ---------------- K3: attention, 1 head per wave, no barriers ----------------
// grid = 4*W blocks; block -> (window b = blk>>2, head group g = blk&3); wave wv -> h = g*4+wv.
// LDS: per-wave P [64][72] bf16 only (36 KB).
__global__ __launch_bounds__(256) void attn_kernel(
    const bf16* __restrict__ q_ws,   // [bw*16+h][64][32]
    const bf16* __restrict__ k_ws,
    const bf16* __restrict__ v_ws,   // [bw*16+h][32][64]
    const float* __restrict__ comb,  // [64][16][4096]  bias[h]+mask[w]
    int wofs,                        // chunk's first window
    bf16* __restrict__ attn_out)     // chunk slice, [rows][512]
{
    __shared__ alignas(16) bf16 P_all[4][64 * 72];
    const int blk = blockIdx.x;
    const int b = blk >> 2, g = blk & 3;
    const int tid = threadIdx.x;
    const int wv = tid >> 6, lane = tid & 63, lq = lane >> 4, lm = lane & 15;
    const int h = g * 4 + wv;
    const v4f z4 = {0.f, 0.f, 0.f, 0.f};

    bf16* P = P_all[wv];
    const size_t qk_base = (size_t)(b * 16 + h) * 64 * 32;
    const float* comb_hw = comb + ((size_t)(((wofs + b) & 63) * 16 + h)) * 4096;

    v8bf qf[4], kf[4];
    #pragma unroll
    for (int i = 0; i < 4; ++i)
        qf[i] = *(const v8bf*)(q_ws + qk_base + (i * 16 + lm) * 32 + lq * 8);
    #pragma unroll
    for (int j = 0; j < 4; ++j)
        kf[j] = *(const v8bf*)(k_ws + qk_base + (j * 16 + lm) * 32 + lq * 8);

    v4f s[4][4];
    #pragma unroll
    for (int i = 0; i < 4; ++i)
        #pragma unroll
        for (int j = 0; j < 4; ++j)
            s[i][j] = __builtin_amdgcn_mfma_f32_16x16x32_bf16(qf[i], kf[j], z4, 0, 0, 0);

    #pragma unroll
    for (int i = 0; i < 4; ++i)
        #pragma unroll
        for (int j = 0; j < 4; ++j)
            #pragma unroll
            for (int r = 0; r < 4; ++r)
                s[i][j][r] += comb_hw[(i * 16 + lq * 4 + r) * 64 + j * 16 + lm];

    float rcpl[4][4];
    #pragma unroll
    for (int i = 0; i < 4; ++i) {
        float mx[4], sm[4];
        #pragma unroll
        for (int r = 0; r < 4; ++r) {
            mx[r] = fmaxf(fmaxf(s[i][0][r], s[i][1][r]), fmaxf(s[i][2][r], s[i][3][r]));
            #pragma unroll
            for (int m = 1; m < 16; m <<= 1) mx[r] = fmaxf(mx[r], __shfl_xor(mx[r], m));
            sm[r] = 0.f;
        }
        #pragma unroll
        for (int j = 0; j < 4; ++j)
            #pragma unroll
            for (int r = 0; r < 4; ++r) {
                s[i][j][r] = __expf(s[i][j][r] - mx[r]);
                sm[r] += s[i][j][r];
            }
        #pragma unroll
        for (int r = 0; r < 4; ++r) {
            #pragma unroll
            for (int m = 1; m < 16; m <<= 1) sm[r] += __shfl_xor(sm[r], m);
            rcpl[i][r] = 1.0f / sm[r];
        }
    }

    // P -> LDS (wave-private; same-wave ds ordering via lgkmcnt)
    #pragma unroll
    for (int i = 0; i < 4; ++i)
        #pragma unroll
        for (int j = 0; j < 4; ++j)
            #pragma unroll
            for (int r = 0; r < 4; ++r)
                P[(i * 16 + lq * 4 + r) * 72 + j * 16 + lm] = (bf16)s[i][j][r];

    const size_t v_base = (size_t)(b * 16 + h) * 32 * 64;
    v4f o[4][2];
    #pragma unroll
    for (int i = 0; i < 4; ++i)
        #pragma unroll
        for (int nt = 0; nt < 2; ++nt) o[i][nt] = z4;
    #pragma unroll
    for (int kk = 0; kk < 2; ++kk) {
        v8bf vf[2], pf[4];
        #pragma unroll
        for (int nt = 0; nt < 2; ++nt)
            vf[nt] = *(const v8bf*)(v_ws + v_base + (nt * 16 + lm) * 64 + kk * 32 + lq * 8);
        #pragma unroll
        for (int i = 0; i < 4; ++i)
            pf[i] = *(const v8bf*)(P + (i * 16 + lm) * 72 + kk * 32 + lq * 8);
        #pragma unroll
        for (int i = 0; i < 4; ++i)
            #pragma unroll
            for (int nt = 0; nt < 2; ++nt)
                o[i][nt] = __builtin_amdgcn_mfma_f32_16x16x32_bf16(pf[i], vf[nt], o[i][nt], 0, 0, 0);
    }
    #pragma unroll
    for (int i = 0; i < 4; ++i)
        #pragma unroll
        for (int nt = 0; nt < 2; ++nt)
            #pragma unroll
            for (int r = 0; r < 4; ++r)
                attn_out[(size_t)(b * 64 + i * 16 + lq * 4 + r) * 512 + h * 32 + nt * 16 + lm] =
                    (bf16)(o[i][nt][r] * rcpl[i][r]);
}

// ---------------- K4: out-projection GEMM, 128x128, BK=32, global_load_lds ----------------
__global__ __launch_bounds__(256) void proj_gemm_kernel(
    const bf16* __restrict__ A,     // [131072][512] attn_out
    const bf16* __restrict__ Bt,    // [512][512] WoT
    const float* __restrict__ b_out,
    float* __restrict__ out)        // [131072][512]
{
    __shared__ alignas(16) bf16 Alds[128 * 32];
    __shared__ alignas(16) bf16 Blds[128 * 32];
    const int bid = blockIdx.x;                       // 4096 blocks
    const int wid = (bid & 7) * 512 + (bid >> 3);     // XCD swizzle
    const int mb = wid >> 2, nb = wid & 3;
    const int tid = threadIdx.x;
    const int wv = tid >> 6, lane = tid & 63, lq = lane >> 4, lm = lane & 15;
    const int wr = wv >> 1, wc = wv & 1;

    v4f acc[4][4];
    #pragma unroll
    for (int i = 0; i < 4; ++i)
        #pragma unroll
        for (int j = 0; j < 4; ++j) acc[i][j] = v4f{0.f, 0.f, 0.f, 0.f};

    const char* aBase = (const char*)A + (size_t)mb * 128 * 1024;
    const char* bBase = (const char*)Bt + (size_t)nb * 128 * 1024;

    for (int kt = 0; kt < 16; ++kt) {
        __syncthreads();
        #pragma unroll
        for (int p = 0; p < 2; ++p) {
            int idx = (p * 4 + wv) * 1024 + lane * 16;
            int row = idx >> 6, kb = idx & 63;
            __builtin_amdgcn_global_load_lds(
                (const __attribute__((address_space(1))) void*)(aBase + (size_t)row * 1024 + kt * 64 + kb),
                (__attribute__((address_space(3))) void*)((char*)Alds + (p * 4 + wv) * 1024),
                16, 0, 0);
            __builtin_amdgcn_global_load_lds(
                (const __attribute__((address_space(1))) void*)(bBase + (size_t)row * 1024 + kt * 64 + kb),
                (__attribute__((address_space(3))) void*)((char*)Blds + (p * 4 + wv) * 1024),
                16, 0, 0);
        }
        __syncthreads();
        v8bf af[4], bfj[4];
        #pragma unroll
        for (int i = 0; i < 4; ++i)
            af[i] = *(const v8bf*)(Alds + (wr * 64 + i * 16 + lm) * 32 + lq * 8);
        #pragma unroll
        for (int j = 0; j < 4; ++j)
            bfj[j] = *(const v8bf*)(Blds + (wc * 64 + j * 16 + lm) * 32 + lq * 8);
        #pragma unroll
        for (int i = 0; i < 4; ++i)
            #pragma unroll
            for (int j = 0; j < 4; ++j)
                acc[i][j] = __builtin_amdgcn_mfma_f32_16x16x32_bf16(af[i], bfj[j], acc[i][j], 0, 0, 0);
    }

    #pragma unroll
    for (int j = 0; j < 4; ++j) {
        int col = nb * 128 + wc * 64 + j * 16 + lm;
        float bo = b_out[col];
        #pragma unroll
        for (int i = 0; i < 4; ++i)
            #pragma unroll
            for (int r = 0; r < 4; ++r)
                out[(size_t)(mb * 128 + wr * 64 + i * 16 + lq * 4 + r) * 512 + col] = acc[i][j][r] + bo;
    }
}

// ---------------- launch ----------------
extern "C" void kernel_launch(void* const* d_in, const int* in_sizes, int n_in,
                              void* d_out, int out_size, void* d_ws, size_t ws_size,
                              hipStream_t stream) {
    (void)in_sizes; (void)n_in; (void)out_size;
    const float* x       = (const float*)d_in[0];
    const float* mask    = (const float*)d_in[1];
    const float* w_qkv   = (const float*)d_in[2];
    const float* tau     = (const float*)d_in[3];
    const float* mlp_w1  = (const float*)d_in[4];
    const float* mlp_b1  = (const float*)d_in[5];
    const float* mlp_w2  = (const float*)d_in[6];
    const float* mlp_b2  = (const float*)d_in[7];
    const float* w_out   = (const float*)d_in[8];
    const float* b_out   = (const float*)d_in[9];
    const float* rel_log = (const float*)d_in[10];
    float* out = (float*)d_out;

    char* ws = (char*)d_ws;
    bf16*  Wt     = (bf16*)(ws);                     // 1,572,864 B
    bf16*  WoT    = (bf16*)(ws + 1572864);           //   524,288 B
    float* bias   = (float*)(ws + 2097152);          //   262,144 B
    float* comb   = (float*)(ws + 2359296);          //  16,777,216 B
    bf16*  shared = (bf16*)(ws + 19136512);          // 134,217,728 B  (xbf, later attn_out)
    char*  qkv_base = ws + 153354240;

    // W windows per chunk; qkv buffers 3*W*65536 B. Total ws top = 153,354,240 + 3*W*65536.
    size_t avail = (ws_size > 153354240ULL) ? ws_size - 153354240ULL : 0;
    int W = 512;                                     // 254.0 MB total, under round-1-proven 270.8 MB
    while (W > 128 && (size_t)W * 196608ULL > avail) W >>= 1;
    const size_t qkbuf = (size_t)W * 65536;          // bytes each for q/k/v
    bf16* qb = (bf16*)qkv_base;
    bf16* kb = (bf16*)(qkv_base + qkbuf);
    bf16* vb = (bf16*)(qkv_base + 2 * qkbuf);

    convert_w_kernel<<<3072, 256, 0, stream>>>(w_qkv, w_out, Wt, WoT);
    bias_kernel<<<16, 256, 0, stream>>>(rel_log, mlp_w1, mlp_b1, mlp_w2, mlp_b2, bias);
    comb_kernel<<<4096, 256, 0, stream>>>(bias, mask, comb);
    convert_x_kernel<<<2048, 256, 0, stream>>>(x, shared);

    const int nchunk = 2048 / W;
    for (int c = 0; c < nchunk; ++c) {
        bf16* slice = shared + (size_t)c * W * 64 * 512;   // xbf for this chunk, then attn_out
        qkv_gemm_kernel<<<6 * W, 256, 0, stream>>>(slice, Wt, tau, qb, kb, vb);
        attn_kernel<<<4 * W, 256, 0, stream>>>(qb, kb, vb, comb, c * W, slice);
    }
    proj_gemm_kernel<<<4096, 256, 0, stream>>>(shared, WoT, b_out, out);
}

// Round 6
// 849.672 us; speedup vs baseline: 1.5442x; 1.0436x over previous
//
#include <hip/hip_runtime.h>
#include <hip/hip_bf16.h>

// WindowAttentionV2: B_NW=2048, N=64, DIM=512, NH=16, DH=32, HID=384, NW=64
// v5: comb pre-swizzled to MFMA frag layout; 2-phase dbuf staging in qkv/proj; W=1024.

typedef __bf16 bf16;
typedef __bf16 v4bf __attribute__((ext_vector_type(4)));
typedef __bf16 v8bf __attribute__((ext_vector_type(8)));
typedef float  v4f  __attribute__((ext_vector_type(4)));

// ---------------- K0a: x fp32 -> bf16 (grid-stride) ----------------
__global__ void convert_x_kernel(const float* __restrict__ x, bf16* __restrict__ xbf) {
    const int stride = gridDim.x * 256;
    for (size_t idx = blockIdx.x * 256 + threadIdx.x; idx < 8388608; idx += stride) {
        const float4* xv = (const float4*)x;
        float4 v0 = xv[idx * 2];
        float4 v1 = xv[idx * 2 + 1];
        v8bf o = { (bf16)v0.x, (bf16)v0.y, (bf16)v0.z, (bf16)v0.w,
                   (bf16)v1.x, (bf16)v1.y, (bf16)v1.z, (bf16)v1.w };
        *(v8bf*)(xbf + idx * 8) = o;
    }
}

// ---------------- K0b: weights -> transposed bf16 ----------------
__global__ void convert_w_kernel(const float* __restrict__ wqkv, const float* __restrict__ wout,
                                 bf16* __restrict__ Wt, bf16* __restrict__ WoT) {
    int idx = blockIdx.x * 256 + threadIdx.x;        // 786,432 threads
    Wt[idx] = (bf16)wqkv[(idx & 511) * 1536 + (idx >> 9)];
    if (idx < 262144) WoT[idx] = (bf16)wout[(idx & 511) * 512 + (idx >> 9)];
}

// ---------------- K1a: meta-MLP bias[h][i][j] ----------------
__global__ void bias_kernel(const float* __restrict__ rel_log, const float* __restrict__ w1,
                            const float* __restrict__ b1, const float* __restrict__ w2,
                            const float* __restrict__ b2, float* __restrict__ bias) {
    int p = blockIdx.x * 256 + threadIdx.x;          // (i,j) pair, 4096 total
    float ra = rel_log[p * 2 + 0];
    float rb = rel_log[p * 2 + 1];
    float acc[16];
    #pragma unroll
    for (int t = 0; t < 16; ++t) acc[t] = 0.f;
    for (int kk = 0; kk < 384; ++kk) {
        float hv = fmaxf(ra * w1[kk] + rb * w1[384 + kk] + b1[kk], 0.f);
        #pragma unroll
        for (int t = 0; t < 16; ++t) acc[t] += hv * w2[kk * 16 + t];
    }
    #pragma unroll
    for (int t = 0; t < 16; ++t) bias[t * 4096 + p] = acc[t] + b2[t];
}

// ---------------- K1b: comb swizzled to MFMA C-frag layout ----------------
// comb[(w*16+h)*4096 + t] where t = (i*4+j)*256 + (lq*16+lm)*4 + r,
// source p = (i*16+lq*4+r)*64 + j*16+lm. Thread (lq,lm) then reads float4 per (i,j).
__global__ void comb_kernel(const float* __restrict__ bias, const float* __restrict__ mask,
                            float* __restrict__ comb) {
    int idx = blockIdx.x * 256 + threadIdx.x;        // 4,194,304 threads (16384 blocks)
    int t = idx & 4095, wh = idx >> 12;
    int w = wh >> 4, h = wh & 15;
    int ij = t >> 8, rem = t & 255;
    int q16 = rem >> 2, r = t & 3;
    int lq = q16 >> 4, lm = q16 & 15;
    int i = ij >> 2, j = ij & 3;
    int p = (i * 16 + lq * 4 + r) * 64 + j * 16 + lm;
    comb[idx] = bias[h * 4096 + p] + mask[w * 4096 + p];
}

// ---------------- K2: qkv GEMM, 2-phase dbuf global_load_lds + cosine-norm epilogue ----------------
// Tile 128x128, BK=32, 4 waves. Grid 6*W blocks (W/2 m-tiles x 12 nb); nb fastest after swizzle.
__global__ __launch_bounds__(256) void qkv_gemm_kernel(
    const bf16* __restrict__ xbf,   // [Mc][512] chunk rows, bf16
    const bf16* __restrict__ Wt,    // [1536][512]
    const float* __restrict__ tau,  // [16]
    bf16* __restrict__ q_ws, bf16* __restrict__ k_ws, bf16* __restrict__ v_ws)
{
    __shared__ alignas(16) bf16 Alds[2][128 * 32];
    __shared__ alignas(16) bf16 Blds[2][128 * 32];
    const int bid = blockIdx.x, nwg = gridDim.x;
    const int wid = (bid & 7) * (nwg >> 3) + (bid >> 3);   // XCD-bijective (nwg%8==0)
    const int nb = wid % 12, mb = wid / 12;                // mb in [0, W/2)

    const int t = threadIdx.x;
    const int wv = t >> 6, lane = t & 63, lq = lane >> 4, lm = lane & 15;
    const int wr = wv >> 1, wc = wv & 1;

    const char* aBase = (const char*)xbf + (size_t)mb * 128 * 1024;
    const char* bBase = (const char*)Wt + (size_t)nb * 128 * 1024;

    auto stage = [&](int buf, int kt) {
        #pragma unroll
        for (int p = 0; p < 2; ++p) {
            int idx = (p * 4 + wv) * 1024 + lane * 16;     // byte offset in 8KB tile
            int row = idx >> 6, kb = idx & 63;
            __builtin_amdgcn_global_load_lds(
                (const __attribute__((address_space(1))) void*)(aBase + (size_t)row * 1024 + kt * 64 + kb),
                (__attribute__((address_space(3))) void*)((char*)Alds + buf * 8192 + (p * 4 + wv) * 1024),
                16, 0, 0);
            __builtin_amdgcn_global_load_lds(
                (const __attribute__((address_space(1))) void*)(bBase + (size_t)row * 1024 + kt * 64 + kb),
                (__attribute__((address_space(3))) void*)((char*)Blds + buf * 8192 + (p * 4 + wv) * 1024),
                16, 0, 0);
        }
    };

    v4f acc[4][4];
    #pragma unroll
    for (int i = 0; i < 4; ++i)
        #pragma unroll
        for (int j = 0; j < 4; ++j) acc[i][j] = v4f{0.f, 0.f, 0.f, 0.f};

    stage(0, 0);
    __syncthreads();
    int cur = 0;
    for (int kt = 0; kt < 16; ++kt) {
        if (kt < 15) stage(cur ^ 1, kt + 1);   // in flight during this tile's MFMA
        v8bf af[4], bfj[4];
        #pragma unroll
        for (int i = 0; i < 4; ++i)
            af[i] = *(const v8bf*)(&Alds[cur][0] + (wr * 64 + i * 16 + lm) * 32 + lq * 8);
        #pragma unroll
        for (int j = 0; j < 4; ++j)
            bfj[j] = *(const v8bf*)(&Blds[cur][0] + (wc * 64 + j * 16 + lm) * 32 + lq * 8);
        #pragma unroll
        for (int i = 0; i < 4; ++i)
            #pragma unroll
            for (int j = 0; j < 4; ++j)
                acc[i][j] = __builtin_amdgcn_mfma_f32_16x16x32_bf16(af[i], bfj[j], acc[i][j], 0, 0, 0);
        __syncthreads();                       // drains next tile's loads + joins waves
        cur ^= 1;
    }

    // epilogue: row = mb*128 + wr*64 + i*16 + lq*4 + r (window bw=mb*2+wr, n=i*16+lq*4+r)
    // col = nb*128 + wc*64 + j*16 + lm; nb<4: q, nb<8: k, else v
    const int bw = mb * 2 + wr;
    if (nb < 8) {
        bf16* dst = (nb < 4) ? q_ws : k_ws;
        const int hbase = (nb & 3) * 4 + wc * 2;
        #pragma unroll
        for (int tpair = 0; tpair < 2; ++tpair) {
            const int h = hbase + tpair;
            const float sc_top = (nb < 4) ? tau[h] : 1.0f;
            #pragma unroll
            for (int i = 0; i < 4; ++i)
                #pragma unroll
                for (int r = 0; r < 4; ++r) {
                    float a0 = acc[i][2 * tpair][r], a1 = acc[i][2 * tpair + 1][r];
                    float ss = a0 * a0 + a1 * a1;
                    #pragma unroll
                    for (int m = 1; m < 16; m <<= 1) ss += __shfl_xor(ss, m);
                    float sc = sc_top / fmaxf(sqrtf(ss), 1e-12f);
                    int n = i * 16 + lq * 4 + r;
                    size_t base = ((size_t)(bw * 16 + h) * 64 + n) * 32;
                    dst[base + lm]      = (bf16)(a0 * sc);
                    dst[base + 16 + lm] = (bf16)(a1 * sc);
                }
        }
    } else {
        #pragma unroll
        for (int j = 0; j < 4; ++j) {
            const int h = (nb - 8) * 4 + wc * 2 + (j >> 1);
            const int dh = (j & 1) * 16 + lm;
            #pragma unroll
            for (int i = 0; i < 4; ++i) {
                v4bf pv = { (bf16)acc[i][j][0], (bf16)acc[i][j][1],
                            (bf16)acc[i][j][2], (bf16)acc[i][j][3] };
                *(v4bf*)(v_ws + ((size_t)(bw * 16 + h) * 32 + dh) * 64 + i * 16 + lq * 4) = pv;
            }
        }
    }
}

// ---------------- K3: attention, 1 head per wave, no barriers ----------------
// grid = 4*W blocks; block -> (window b = blk>>2, head group g = blk&3); wave wv -> h = g*4+wv.
__global__ __launch_bounds__(256) void attn_kernel(
    const bf16* __restrict__ q_ws,   // [bw*16+h][64][32]
    const bf16* __restrict__ k_ws,
    const bf16* __restrict__ v_ws,   // [bw*16+h][32][64]
    const float* __restrict__ comb,  // [64][16][4096] swizzled (bias[h]+mask[w])
    int wofs,                        // chunk's first window
    bf16* __restrict__ attn_out)     // chunk slice, [rows][512]
{
    __shared__ alignas(16) bf16 P_all[4][64 * 72];
    const int blk = blockIdx.x;
    const int b = blk >> 2, g = blk & 3;
    const int tid = threadIdx.x;
    const int wv = tid >> 6, lane = tid & 63, lq = lane >> 4, lm = lane & 15;
    const int h = g * 4 + wv;
    const v4f z4 = {0.f, 0.f, 0.f, 0.f};

    bf16* P = P_all[wv];
    const size_t qk_base = (size_t)(b * 16 + h) * 64 * 32;
    const float* comb_hw = comb + ((size_t)(((wofs + b) & 63) * 16 + h)) * 4096
                                + (lq * 16 + lm) * 4;   // thread's frag base

    v8bf qf[4], kf[4];
    #pragma unroll
    for (int i = 0; i < 4; ++i)
        qf[i] = *(const v8bf*)(q_ws + qk_base + (i * 16 + lm) * 32 + lq * 8);
    #pragma unroll
    for (int j = 0; j < 4; ++j)
        kf[j] = *(const v8bf*)(k_ws + qk_base + (j * 16 + lm) * 32 + lq * 8);

    v4f s[4][4];
    #pragma unroll
    for (int i = 0; i < 4; ++i)
        #pragma unroll
        for (int j = 0; j < 4; ++j)
            s[i][j] = __builtin_amdgcn_mfma_f32_16x16x32_bf16(qf[i], kf[j], z4, 0, 0, 0);

    // + (bias+mask), frag-layout float4 loads (coalesced)
    #pragma unroll
    for (int i = 0; i < 4; ++i)
        #pragma unroll
        for (int j = 0; j < 4; ++j) {
            float4 cv = *(const float4*)(comb_hw + (i * 4 + j) * 256);
            s[i][j][0] += cv.x; s[i][j][1] += cv.y;
            s[i][j][2] += cv.z; s[i][j][3] += cv.w;
        }

    float rcpl[4][4];
    #pragma unroll
    for (int i = 0; i < 4; ++i) {
        float mx[4], sm[4];
        #pragma unroll
        for (int r = 0; r < 4; ++r) {
            mx[r] = fmaxf(fmaxf(s[i][0][r], s[i][1][r]), fmaxf(s[i][2][r], s[i][3][r]));
            #pragma unroll
            for (int m = 1; m < 16; m <<= 1) mx[r] = fmaxf(mx[r], __shfl_xor(mx[r], m));
            sm[r] = 0.f;
        }
        #pragma unroll
        for (int j = 0; j < 4; ++j)
            #pragma unroll
            for (int r = 0; r < 4; ++r) {
                s[i][j][r] = __expf(s[i][j][r] - mx[r]);
                sm[r] += s[i][j][r];
            }
        #pragma unroll
        for (int r = 0; r < 4; ++r) {
            #pragma unroll
            for (int m = 1; m < 16; m <<= 1) sm[r] += __shfl_xor(sm[r], m);
            rcpl[i][r] = 1.0f / sm[r];
        }
    }

    // P -> LDS (wave-private; same-wave ds ordering via lgkmcnt)
    #pragma unroll
    for (int i = 0; i < 4; ++i)
        #pragma unroll
        for (int j = 0; j < 4; ++j)
            #pragma unroll
            for (int r = 0; r < 4; ++r)
                P[(i * 16 + lq * 4 + r) * 72 + j * 16 + lm] = (bf16)s[i][j][r];

    const size_t v_base = (size_t)(b * 16 + h) * 32 * 64;
    v4f o[4][2];
    #pragma unroll
    for (int i = 0; i < 4; ++i)
        #pragma unroll
        for (int nt = 0; nt < 2; ++nt) o[i][nt] = z4;
    #pragma unroll
    for (int kk = 0; kk < 2; ++kk) {
        v8bf vf[2], pf[4];
        #pragma unroll
        for (int nt = 0; nt < 2; ++nt)
            vf[nt] = *(const v8bf*)(v_ws + v_base + (nt * 16 + lm) * 64 + kk * 32 + lq * 8);
        #pragma unroll
        for (int i = 0; i < 4; ++i)
            pf[i] = *(const v8bf*)(P + (i * 16 + lm) * 72 + kk * 32 + lq * 8);
        #pragma unroll
        for (int i = 0; i < 4; ++i)
            #pragma unroll
            for (int nt = 0; nt < 2; ++nt)
                o[i][nt] = __builtin_amdgcn_mfma_f32_16x16x32_bf16(pf[i], vf[nt], o[i][nt], 0, 0, 0);
    }
    #pragma unroll
    for (int i = 0; i < 4; ++i)
        #pragma unroll
        for (int nt = 0; nt < 2; ++nt)
            #pragma unroll
            for (int r = 0; r < 4; ++r)
                attn_out[(size_t)(b * 64 + i * 16 + lq * 4 + r) * 512 + h * 32 + nt * 16 + lm] =
                    (bf16)(o[i][nt][r] * rcpl[i][r]);
}

// ---------------- K4: out-projection GEMM, 2-phase dbuf ----------------
__global__ __launch_bounds__(256) void proj_gemm_kernel(
    const bf16* __restrict__ A,     // [131072][512] attn_out
    const bf16* __restrict__ Bt,    // [512][512] WoT
    const float* __restrict__ b_out,
    float* __restrict__ out)        // [131072][512]
{
    __shared__ alignas(16) bf16 Alds[2][128 * 32];
    __shared__ alignas(16) bf16 Blds[2][128 * 32];
    const int bid = blockIdx.x;                       // 4096 blocks
    const int wid = (bid & 7) * 512 + (bid >> 3);     // XCD swizzle
    const int mb = wid >> 2, nb = wid & 3;            // nb fastest: A-tile reuse
    const int tid = threadIdx.x;
    const int wv = tid >> 6, lane = tid & 63, lq = lane >> 4, lm = lane & 15;
    const int wr = wv >> 1, wc = wv & 1;

    const char* aBase = (const char*)A + (size_t)mb * 128 * 1024;
    const char* bBase = (const char*)Bt + (size_t)nb * 128 * 1024;

    auto stage = [&](int buf, int kt) {
        #pragma unroll
        for (int p = 0; p < 2; ++p) {
            int idx = (p * 4 + wv) * 1024 + lane * 16;
            int row = idx >> 6, kb = idx & 63;
            __builtin_amdgcn_global_load_lds(
                (const __attribute__((address_space(1))) void*)(aBase + (size_t)row * 1024 + kt * 64 + kb),
                (__attribute__((address_space(3))) void*)((char*)Alds + buf * 8192 + (p * 4 + wv) * 1024),
                16, 0, 0);
            __builtin_amdgcn_global_load_lds(
                (const __attribute__((address_space(1))) void*)(bBase + (size_t)row * 1024 + kt * 64 + kb),
                (__attribute__((address_space(3))) void*)((char*)Blds + buf * 8192 + (p * 4 + wv) * 1024),
                16, 0, 0);
        }
    };

    v4f acc[4][4];
    #pragma unroll
    for (int i = 0; i < 4; ++i)
        #pragma unroll
        for (int j = 0; j < 4; ++j) acc[i][j] = v4f{0.f, 0.f, 0.f, 0.f};

    stage(0, 0);
    __syncthreads();
    int cur = 0;
    for (int kt = 0; kt < 16; ++kt) {
        if (kt < 15) stage(cur ^ 1, kt + 1);
        v8bf af[4], bfj[4];
        #pragma unroll
        for (int i = 0; i < 4; ++i)
            af[i] = *(const v8bf*)(&Alds[cur][0] + (wr * 64 + i * 16 + lm) * 32 + lq * 8);
        #pragma unroll
        for (int j = 0; j < 4; ++j)
            bfj[j] = *(const v8bf*)(&Blds[cur][0] + (wc * 64 + j * 16 + lm) * 32 + lq * 8);
        #pragma unroll
        for (int i = 0; i < 4; ++i)
            #pragma unroll
            for (int j = 0; j < 4; ++j)
                acc[i][j] = __builtin_amdgcn_mfma_f32_16x16x32_bf16(af[i], bfj[j], acc[i][j], 0, 0, 0);
        __syncthreads();
        cur ^= 1;
    }

    #pragma unroll
    for (int j = 0; j < 4; ++j) {
        int col = nb * 128 + wc * 64 + j * 16 + lm;
        float bo = b_out[col];
        #pragma unroll
        for (int i = 0; i < 4; ++i)
            #pragma unroll
            for (int r = 0; r < 4; ++r)
                out[(size_t)(mb * 128 + wr * 64 + i * 16 + lq * 4 + r) * 512 + col] = acc[i][j][r] + bo;
    }
}

// ---------------- launch ----------------
extern "C" void kernel_launch(void* const* d_in, const int* in_sizes, int n_in,
                              void* d_out, int out_size, void* d_ws, size_t ws_size,
                              hipStream_t stream) {
    (void)in_sizes; (void)n_in; (void)out_size;
    const float* x       = (const float*)d_in[0];
    const float* mask    = (const float*)d_in[1];
    const float* w_qkv   = (const float*)d_in[2];
    const float* tau     = (const float*)d_in[3];
    const float* mlp_w1  = (const float*)d_in[4];
    const float* mlp_b1  = (const float*)d_in[5];
    const float* mlp_w2  = (const float*)d_in[6];
    const float* mlp_b2  = (const float*)d_in[7];
    const float* w_out   = (const float*)d_in[8];
    const float* b_out   = (const float*)d_in[9];
    const float* rel_log = (const float*)d_in[10];
    float* out = (float*)d_out;

    char* ws = (char*)d_ws;
    bf16*  Wt     = (bf16*)(ws);                     // 1,572,864 B
    bf16*  WoT    = (bf16*)(ws + 1572864);           //   524,288 B
    float* bias   = (float*)(ws + 2097152);          //   262,144 B
    float* comb   = (float*)(ws + 2359296);          //  16,777,216 B
    bf16*  shared = (bf16*)(ws + 19136512);          // 134,217,728 B  (xbf, later attn_out)
    char*  qkv_base = ws + 153354240;

    // W windows per chunk; qkv buffers 3*W*65536 B. ws top = 153,354,240 + 3*W*65536.
    size_t avail = (ws_size > 153354240ULL) ? ws_size - 153354240ULL : 0;
    int W = 1024;                                    // 354.7 MB total (ws is ~1 GB per fillBuffer evidence)
    while (W > 128 && (size_t)W * 196608ULL > avail) W >>= 1;
    const size_t qkbuf = (size_t)W * 65536;          // bytes each for q/k/v
    bf16* qb = (bf16*)qkv_base;
    bf16* kb = (bf16*)(qkv_base + qkbuf);
    bf16* vb = (bf16*)(qkv_base + 2 * qkbuf);

    convert_w_kernel<<<3072, 256, 0, stream>>>(w_qkv, w_out, Wt, WoT);
    bias_kernel<<<16, 256, 0, stream>>>(rel_log, mlp_w1, mlp_b1, mlp_w2, mlp_b2, bias);
    comb_kernel<<<16384, 256, 0, stream>>>(bias, mask, comb);
    convert_x_kernel<<<2048, 256, 0, stream>>>(x, shared);

    const int nchunk = 2048 / W;
    for (int c = 0; c < nchunk; ++c) {
        bf16* slice = shared + (size_t)c * W * 64 * 512;   // xbf for this chunk, then attn_out
        qkv_gemm_kernel<<<6 * W, 256, 0, stream>>>(slice, Wt, tau, qb, kb, vb);
        attn_kernel<<<4 * W, 256, 0, stream>>>(qb, kb, vb, comb, c * W, slice);
    }
    proj_gemm_kernel<<<4096, 256, 0, stream>>>(shared, WoT, b_out, out);
}

// Round 7
// 777.497 us; speedup vs baseline: 1.6876x; 1.0928x over previous
//
#include <hip/hip_runtime.h>
#include <hip/hip_bf16.h>

// WindowAttentionV2: B_NW=2048, N=64, DIM=512, NH=16, DH=32, HID=384, NW=64
// v6: norm moved qkv->attn (frag-local, 2-shfl); swapped QK^T (lane-local softmax);
//     comb swizzled for S^T frag layout; vectorized P stores; 2-phase dbuf GEMMs.

typedef __bf16 bf16;
typedef __bf16 v4bf __attribute__((ext_vector_type(4)));
typedef __bf16 v8bf __attribute__((ext_vector_type(8)));
typedef float  v4f  __attribute__((ext_vector_type(4)));

// ---------------- K0a: x fp32 -> bf16 (grid-stride) ----------------
__global__ void convert_x_kernel(const float* __restrict__ x, bf16* __restrict__ xbf) {
    const int stride = gridDim.x * 256;
    for (size_t idx = blockIdx.x * 256 + threadIdx.x; idx < 8388608; idx += stride) {
        const float4* xv = (const float4*)x;
        float4 v0 = xv[idx * 2];
        float4 v1 = xv[idx * 2 + 1];
        v8bf o = { (bf16)v0.x, (bf16)v0.y, (bf16)v0.z, (bf16)v0.w,
                   (bf16)v1.x, (bf16)v1.y, (bf16)v1.z, (bf16)v1.w };
        *(v8bf*)(xbf + idx * 8) = o;
    }
}

// ---------------- K0b: weights -> transposed bf16 ----------------
__global__ void convert_w_kernel(const float* __restrict__ wqkv, const float* __restrict__ wout,
                                 bf16* __restrict__ Wt, bf16* __restrict__ WoT) {
    int idx = blockIdx.x * 256 + threadIdx.x;        // 786,432 threads
    Wt[idx] = (bf16)wqkv[(idx & 511) * 1536 + (idx >> 9)];
    if (idx < 262144) WoT[idx] = (bf16)wout[(idx & 511) * 512 + (idx >> 9)];
}

// ---------------- K1a: meta-MLP bias[h][i][j] ----------------
__global__ void bias_kernel(const float* __restrict__ rel_log, const float* __restrict__ w1,
                            const float* __restrict__ b1, const float* __restrict__ w2,
                            const float* __restrict__ b2, float* __restrict__ bias) {
    int p = blockIdx.x * 256 + threadIdx.x;          // (i,j) pair, 4096 total
    float ra = rel_log[p * 2 + 0];
    float rb = rel_log[p * 2 + 1];
    float acc[16];
    #pragma unroll
    for (int t = 0; t < 16; ++t) acc[t] = 0.f;
    for (int kk = 0; kk < 384; ++kk) {
        float hv = fmaxf(ra * w1[kk] + rb * w1[384 + kk] + b1[kk], 0.f);
        #pragma unroll
        for (int t = 0; t < 16; ++t) acc[t] += hv * w2[kk * 16 + t];
    }
    #pragma unroll
    for (int t = 0; t < 16; ++t) bias[t * 4096 + p] = acc[t] + b2[t];
}

// ---------------- K1b: comb swizzled for the SWAPPED (S^T) frag layout ----------------
// idx = (w*16+h)*4096 + (j*4+i)*256 + (lq*16+lm)*4 + r  maps to  p = (q)*64 + k,
// with q = i*16+lm, k = j*16+lq*4+r.
__global__ void comb_kernel(const float* __restrict__ bias, const float* __restrict__ mask,
                            float* __restrict__ comb) {
    int idx = blockIdx.x * 256 + threadIdx.x;        // 4,194,304 threads (16384 blocks)
    int t = idx & 4095, wh = idx >> 12;
    int w = wh >> 4, h = wh & 15;
    int ji = t >> 8, rem = t & 255;
    int j = ji >> 2, i = ji & 3;
    int q16 = rem >> 2, r = t & 3;
    int lq = q16 >> 4, lm = q16 & 15;
    int p = (i * 16 + lm) * 64 + j * 16 + lq * 4 + r;
    comb[idx] = bias[h * 4096 + p] + mask[w * 4096 + p];
}

// ---------------- K2: qkv GEMM, 2-phase dbuf global_load_lds, plain bf16 epilogue ----------------
// Tile 128x128, BK=32, 4 waves. Grid 6*W blocks (W/2 m-tiles x 12 nb); nb fastest after swizzle.
// Outputs (UNNORMALIZED): q_ws/k_ws [bw*16+h][n][dh] bf16, v_ws [bw*16+h][dh][n] bf16.
__global__ __launch_bounds__(256) void qkv_gemm_kernel(
    const bf16* __restrict__ xbf,   // [Mc][512] chunk rows, bf16
    const bf16* __restrict__ Wt,    // [1536][512]
    bf16* __restrict__ q_ws, bf16* __restrict__ k_ws, bf16* __restrict__ v_ws)
{
    __shared__ alignas(16) bf16 Alds[2][128 * 32];
    __shared__ alignas(16) bf16 Blds[2][128 * 32];
    const int bid = blockIdx.x, nwg = gridDim.x;
    const int wid = (bid & 7) * (nwg >> 3) + (bid >> 3);   // XCD-bijective (nwg%8==0)
    const int nb = wid % 12, mb = wid / 12;                // mb in [0, W/2)

    const int t = threadIdx.x;
    const int wv = t >> 6, lane = t & 63, lq = lane >> 4, lm = lane & 15;
    const int wr = wv >> 1, wc = wv & 1;

    const char* aBase = (const char*)xbf + (size_t)mb * 128 * 1024;
    const char* bBase = (const char*)Wt + (size_t)nb * 128 * 1024;

    auto stage = [&](int buf, int kt) {
        #pragma unroll
        for (int p = 0; p < 2; ++p) {
            int idx = (p * 4 + wv) * 1024 + lane * 16;     // byte offset in 8KB tile
            int row = idx >> 6, kb = idx & 63;
            __builtin_amdgcn_global_load_lds(
                (const __attribute__((address_space(1))) void*)(aBase + (size_t)row * 1024 + kt * 64 + kb),
                (__attribute__((address_space(3))) void*)((char*)Alds + buf * 8192 + (p * 4 + wv) * 1024),
                16, 0, 0);
            __builtin_amdgcn_global_load_lds(
                (const __attribute__((address_space(1))) void*)(bBase + (size_t)row * 1024 + kt * 64 + kb),
                (__attribute__((address_space(3))) void*)((char*)Blds + buf * 8192 + (p * 4 + wv) * 1024),
                16, 0, 0);
        }
    };

    v4f acc[4][4];
    #pragma unroll
    for (int i = 0; i < 4; ++i)
        #pragma unroll
        for (int j = 0; j < 4; ++j) acc[i][j] = v4f{0.f, 0.f, 0.f, 0.f};

    stage(0, 0);
    __syncthreads();
    int cur = 0;
    for (int kt = 0; kt < 16; ++kt) {
        if (kt < 15) stage(cur ^ 1, kt + 1);   // in flight during this tile's MFMA
        v8bf af[4], bfj[4];
        #pragma unroll
        for (int i = 0; i < 4; ++i)
            af[i] = *(const v8bf*)(&Alds[cur][0] + (wr * 64 + i * 16 + lm) * 32 + lq * 8);
        #pragma unroll
        for (int j = 0; j < 4; ++j)
            bfj[j] = *(const v8bf*)(&Blds[cur][0] + (wc * 64 + j * 16 + lm) * 32 + lq * 8);
        #pragma unroll
        for (int i = 0; i < 4; ++i)
            #pragma unroll
            for (int j = 0; j < 4; ++j)
                acc[i][j] = __builtin_amdgcn_mfma_f32_16x16x32_bf16(af[i], bfj[j], acc[i][j], 0, 0, 0);
        __syncthreads();                       // drains next tile's loads + joins waves
        cur ^= 1;
    }

    // epilogue (no norm): row n = i*16+lq*4+r (window bw=mb*2+wr), col = nb*128+wc*64+j*16+lm
    const int bw = mb * 2 + wr;
    if (nb < 8) {
        bf16* dst = (nb < 4) ? q_ws : k_ws;
        const int hbase = (nb & 3) * 4 + wc * 2;
        #pragma unroll
        for (int tpair = 0; tpair < 2; ++tpair) {
            const int h = hbase + tpair;
            #pragma unroll
            for (int i = 0; i < 4; ++i)
                #pragma unroll
                for (int r = 0; r < 4; ++r) {
                    int n = i * 16 + lq * 4 + r;
                    size_t base = ((size_t)(bw * 16 + h) * 64 + n) * 32;
                    dst[base + lm]      = (bf16)acc[i][2 * tpair][r];
                    dst[base + 16 + lm] = (bf16)acc[i][2 * tpair + 1][r];
                }
        }
    } else {
        #pragma unroll
        for (int j = 0; j < 4; ++j) {
            const int h = (nb - 8) * 4 + wc * 2 + (j >> 1);
            const int dh = (j & 1) * 16 + lm;
            #pragma unroll
            for (int i = 0; i < 4; ++i) {
                v4bf pv = { (bf16)acc[i][j][0], (bf16)acc[i][j][1],
                            (bf16)acc[i][j][2], (bf16)acc[i][j][3] };
                *(v4bf*)(v_ws + ((size_t)(bw * 16 + h) * 32 + dh) * 64 + i * 16 + lq * 4) = pv;
            }
        }
    }
}

// ---------------- K3: attention, swapped QK^T, frag-local norm, 1 head/wave ----------------
// grid = 4*W blocks; block -> (window b = blk>>2, head group g = blk&3); wave wv -> h = g*4+wv.
__global__ __launch_bounds__(256) void attn_kernel(
    const bf16* __restrict__ q_ws,   // [bw*16+h][64][32] unnormalized
    const bf16* __restrict__ k_ws,
    const bf16* __restrict__ v_ws,   // [bw*16+h][32][64]
    const float* __restrict__ comb,  // [64][16][4096] swizzled for S^T frags
    const float* __restrict__ tau,   // [16]
    int wofs,                        // chunk's first window
    bf16* __restrict__ attn_out)     // chunk slice, [rows][512]
{
    __shared__ alignas(16) bf16 P_all[4][64 * 72];
    const int blk = blockIdx.x;
    const int b = blk >> 2, g = blk & 3;
    const int tid = threadIdx.x;
    const int wv = tid >> 6, lane = tid & 63, lq = lane >> 4, lm = lane & 15;
    const int h = g * 4 + wv;
    const v4f z4 = {0.f, 0.f, 0.f, 0.f};

    bf16* P = P_all[wv];
    const size_t qk_base = (size_t)(b * 16 + h) * 64 * 32;
    const float* comb_hw = comb + ((size_t)(((wofs + b) & 63) * 16 + h)) * 4096
                                + (lq * 16 + lm) * 4;
    const float tau_h = tau[h];

    v8bf qf[4], kf[4];
    #pragma unroll
    for (int i = 0; i < 4; ++i)
        qf[i] = *(const v8bf*)(q_ws + qk_base + (i * 16 + lm) * 32 + lq * 8);
    #pragma unroll
    for (int j = 0; j < 4; ++j)
        kf[j] = *(const v8bf*)(k_ws + qk_base + (j * 16 + lm) * 32 + lq * 8);

    // frag-local L2 norms: 8 in-lane squares + 2 shfl over lq groups; tau folded into q-scale
    #pragma unroll
    for (int i = 0; i < 4; ++i) {
        float a = 0.f;
        #pragma unroll
        for (int e = 0; e < 8; ++e) { float f = (float)qf[i][e]; a = fmaf(f, f, a); }
        a += __shfl_xor(a, 16); a += __shfl_xor(a, 32);
        float sc = tau_h / fmaxf(sqrtf(a), 1e-12f);
        #pragma unroll
        for (int e = 0; e < 8; ++e) qf[i][e] = (bf16)((float)qf[i][e] * sc);
    }
    #pragma unroll
    for (int j = 0; j < 4; ++j) {
        float a = 0.f;
        #pragma unroll
        for (int e = 0; e < 8; ++e) { float f = (float)kf[j][e]; a = fmaf(f, f, a); }
        a += __shfl_xor(a, 16); a += __shfl_xor(a, 32);
        float sc = 1.0f / fmaxf(sqrtf(a), 1e-12f);
        #pragma unroll
        for (int e = 0; e < 8; ++e) kf[j][e] = (bf16)((float)kf[j][e] * sc);
    }

    // S^T = K̂ Q̂^T: lane holds (k = j*16+lq*4+r, q = i*16+lm)
    v4f st[4][4];
    #pragma unroll
    for (int j = 0; j < 4; ++j)
        #pragma unroll
        for (int i = 0; i < 4; ++i)
            st[j][i] = __builtin_amdgcn_mfma_f32_16x16x32_bf16(kf[j], qf[i], z4, 0, 0, 0);

    // + (bias+mask) in S^T frag layout
    #pragma unroll
    for (int j = 0; j < 4; ++j)
        #pragma unroll
        for (int i = 0; i < 4; ++i) {
            float4 cv = *(const float4*)(comb_hw + (j * 4 + i) * 256);
            st[j][i][0] += cv.x; st[j][i][1] += cv.y;
            st[j][i][2] += cv.z; st[j][i][3] += cv.w;
        }

    // softmax over k per q-col i: 16 in-lane + 2 shfl; fold 1/l into P; vectorized P store
    #pragma unroll
    for (int i = 0; i < 4; ++i) {
        float mx = st[0][i][0];
        #pragma unroll
        for (int j = 0; j < 4; ++j)
            #pragma unroll
            for (int r = 0; r < 4; ++r) mx = fmaxf(mx, st[j][i][r]);
        mx = fmaxf(mx, __shfl_xor(mx, 16));
        mx = fmaxf(mx, __shfl_xor(mx, 32));
        float sm = 0.f;
        #pragma unroll
        for (int j = 0; j < 4; ++j)
            #pragma unroll
            for (int r = 0; r < 4; ++r) {
                float e = __expf(st[j][i][r] - mx);
                st[j][i][r] = e; sm += e;
            }
        sm += __shfl_xor(sm, 16); sm += __shfl_xor(sm, 32);
        float rcp = 1.0f / sm;
        #pragma unroll
        for (int j = 0; j < 4; ++j) {
            v4bf pv = { (bf16)(st[j][i][0] * rcp), (bf16)(st[j][i][1] * rcp),
                        (bf16)(st[j][i][2] * rcp), (bf16)(st[j][i][3] * rcp) };
            *(v4bf*)(P + (i * 16 + lm) * 72 + j * 16 + lq * 4) = pv;
        }
    }

    // O = P̂ V (P already normalized): pf = P rows, vf = V^T rows
    const size_t v_base = (size_t)(b * 16 + h) * 32 * 64;
    v4f o[4][2];
    #pragma unroll
    for (int i = 0; i < 4; ++i)
        #pragma unroll
        for (int nt = 0; nt < 2; ++nt) o[i][nt] = z4;
    #pragma unroll
    for (int kk = 0; kk < 2; ++kk) {
        v8bf vf[2], pf[4];
        #pragma unroll
        for (int nt = 0; nt < 2; ++nt)
            vf[nt] = *(const v8bf*)(v_ws + v_base + (nt * 16 + lm) * 64 + kk * 32 + lq * 8);
        #pragma unroll
        for (int i = 0; i < 4; ++i)
            pf[i] = *(const v8bf*)(P + (i * 16 + lm) * 72 + kk * 32 + lq * 8);
        #pragma unroll
        for (int i = 0; i < 4; ++i)
            #pragma unroll
            for (int nt = 0; nt < 2; ++nt)
                o[i][nt] = __builtin_amdgcn_mfma_f32_16x16x32_bf16(pf[i], vf[nt], o[i][nt], 0, 0, 0);
    }
    #pragma unroll
    for (int i = 0; i < 4; ++i)
        #pragma unroll
        for (int nt = 0; nt < 2; ++nt)
            #pragma unroll
            for (int r = 0; r < 4; ++r)
                attn_out[(size_t)(b * 64 + i * 16 + lq * 4 + r) * 512 + h * 32 + nt * 16 + lm] =
                    (bf16)o[i][nt][r];
}

// ---------------- K4: out-projection GEMM, 2-phase dbuf ----------------
__global__ __launch_bounds__(256) void proj_gemm_kernel(
    const bf16* __restrict__ A,     // [131072][512] attn_out
    const bf16* __restrict__ Bt,    // [512][512] WoT
    const float* __restrict__ b_out,
    float* __restrict__ out)        // [131072][512]
{
    __shared__ alignas(16) bf16 Alds[2][128 * 32];
    __shared__ alignas(16) bf16 Blds[2][128 * 32];
    const int bid = blockIdx.x;                       // 4096 blocks
    const int wid = (bid & 7) * 512 + (bid >> 3);     // XCD swizzle
    const int mb = wid >> 2, nb = wid & 3;            // nb fastest: A-tile reuse
    const int tid = threadIdx.x;
    const int wv = tid >> 6, lane = tid & 63, lq = lane >> 4, lm = lane & 15;
    const int wr = wv >> 1, wc = wv & 1;

    const char* aBase = (const char*)A + (size_t)mb * 128 * 1024;
    const char* bBase = (const char*)Bt + (size_t)nb * 128 * 1024;

    auto stage = [&](int buf, int kt) {
        #pragma unroll
        for (int p = 0; p < 2; ++p) {
            int idx = (p * 4 + wv) * 1024 + lane * 16;
            int row = idx >> 6, kb = idx & 63;
            __builtin_amdgcn_global_load_lds(
                (const __attribute__((address_space(1))) void*)(aBase + (size_t)row * 1024 + kt * 64 + kb),
                (__attribute__((address_space(3))) void*)((char*)Alds + buf * 8192 + (p * 4 + wv) * 1024),
                16, 0, 0);
            __builtin_amdgcn_global_load_lds(
                (const __attribute__((address_space(1))) void*)(bBase + (size_t)row * 1024 + kt * 64 + kb),
                (__attribute__((address_space(3))) void*)((char*)Blds + buf * 8192 + (p * 4 + wv) * 1024),
                16, 0, 0);
        }
    };

    v4f acc[4][4];
    #pragma unroll
    for (int i = 0; i < 4; ++i)
        #pragma unroll
        for (int j = 0; j < 4; ++j) acc[i][j] = v4f{0.f, 0.f, 0.f, 0.f};

    stage(0, 0);
    __syncthreads();
    int cur = 0;
    for (int kt = 0; kt < 16; ++kt) {
        if (kt < 15) stage(cur ^ 1, kt + 1);
        v8bf af[4], bfj[4];
        #pragma unroll
        for (int i = 0; i < 4; ++i)
            af[i] = *(const v8bf*)(&Alds[cur][0] + (wr * 64 + i * 16 + lm) * 32 + lq * 8);
        #pragma unroll
        for (int j = 0; j < 4; ++j)
            bfj[j] = *(const v8bf*)(&Blds[cur][0] + (wc * 64 + j * 16 + lm) * 32 + lq * 8);
        #pragma unroll
        for (int i = 0; i < 4; ++i)
            #pragma unroll
            for (int j = 0; j < 4; ++j)
                acc[i][j] = __builtin_amdgcn_mfma_f32_16x16x32_bf16(af[i], bfj[j], acc[i][j], 0, 0, 0);
        __syncthreads();
        cur ^= 1;
    }

    #pragma unroll
    for (int j = 0; j < 4; ++j) {
        int col = nb * 128 + wc * 64 + j * 16 + lm;
        float bo = b_out[col];
        #pragma unroll
        for (int i = 0; i < 4; ++i)
            #pragma unroll
            for (int r = 0; r < 4; ++r)
                out[(size_t)(mb * 128 + wr * 64 + i * 16 + lq * 4 + r) * 512 + col] = acc[i][j][r] + bo;
    }
}

// ---------------- launch ----------------
extern "C" void kernel_launch(void* const* d_in, const int* in_sizes, int n_in,
                              void* d_out, int out_size, void* d_ws, size_t ws_size,
                              hipStream_t stream) {
    (void)in_sizes; (void)n_in; (void)out_size;
    const float* x       = (const float*)d_in[0];
    const float* mask    = (const float*)d_in[1];
    const float* w_qkv   = (const float*)d_in[2];
    const float* tau     = (const float*)d_in[3];
    const float* mlp_w1  = (const float*)d_in[4];
    const float* mlp_b1  = (const float*)d_in[5];
    const float* mlp_w2  = (const float*)d_in[6];
    const float* mlp_b2  = (const float*)d_in[7];
    const float* w_out   = (const float*)d_in[8];
    const float* b_out   = (const float*)d_in[9];
    const float* rel_log = (const float*)d_in[10];
    float* out = (float*)d_out;

    char* ws = (char*)d_ws;
    bf16*  Wt     = (bf16*)(ws);                     // 1,572,864 B
    bf16*  WoT    = (bf16*)(ws + 1572864);           //   524,288 B
    float* bias   = (float*)(ws + 2097152);          //   262,144 B
    float* comb   = (float*)(ws + 2359296);          //  16,777,216 B
    bf16*  shared = (bf16*)(ws + 19136512);          // 134,217,728 B  (xbf, later attn_out)
    char*  qkv_base = ws + 153354240;

    // W windows per chunk; qkv buffers 3*W*65536 B. ws top = 153,354,240 + 3*W*65536.
    size_t avail = (ws_size > 153354240ULL) ? ws_size - 153354240ULL : 0;
    int W = 1024;                                    // 354.7 MB total (ws ~1 GB per fillBuffer evidence)
    while (W > 128 && (size_t)W * 196608ULL > avail) W >>= 1;
    const size_t qkbuf = (size_t)W * 65536;          // bytes each for q/k/v
    bf16* qb = (bf16*)qkv_base;
    bf16* kb = (bf16*)(qkv_base + qkbuf);
    bf16* vb = (bf16*)(qkv_base + 2 * qkbuf);

    convert_w_kernel<<<3072, 256, 0, stream>>>(w_qkv, w_out, Wt, WoT);
    bias_kernel<<<16, 256, 0, stream>>>(rel_log, mlp_w1, mlp_b1, mlp_w2, mlp_b2, bias);
    comb_kernel<<<16384, 256, 0, stream>>>(bias, mask, comb);
    convert_x_kernel<<<2048, 256, 0, stream>>>(x, shared);

    const int nchunk = 2048 / W;
    for (int c = 0; c < nchunk; ++c) {
        bf16* slice = shared + (size_t)c * W * 64 * 512;   // xbf for this chunk, then attn_out
        qkv_gemm_kernel<<<6 * W, 256, 0, stream>>>(slice, Wt, qb, kb, vb);
        attn_kernel<<<4 * W, 256, 0, stream>>>(qb, kb, vb, comb, tau, c * W, slice);
    }
    proj_gemm_kernel<<<4096, 256, 0, stream>>>(shared, WoT, b_out, out);
}

// Round 10
// 773.515 us; speedup vs baseline: 1.6963x; 1.0051x over previous
//
#include <hip/hip_runtime.h>
#include <hip/hip_bf16.h>

// WindowAttentionV2: B_NW=2048, N=64, DIM=512, NH=16, DH=32, HID=384, NW=64
// v8 = v6 (known-good: __syncthreads 2-phase dbuf, swapped QK^T attn, frag-local norm)
//      + W=2048 single chunk (ws_size = 1 GiB per round-5 poison evidence).
// Deliberately NO raw s_barrier / inline-asm vmcnt after two container deaths -
// this build re-establishes the verified baseline.

typedef __bf16 bf16;
typedef __bf16 v4bf __attribute__((ext_vector_type(4)));
typedef __bf16 v8bf __attribute__((ext_vector_type(8)));
typedef float  v4f  __attribute__((ext_vector_type(4)));

// ---------------- K0a: x fp32 -> bf16 (grid-stride) ----------------
__global__ void convert_x_kernel(const float* __restrict__ x, bf16* __restrict__ xbf) {
    const int stride = gridDim.x * 256;
    for (size_t idx = blockIdx.x * 256 + threadIdx.x; idx < 8388608; idx += stride) {
        const float4* xv = (const float4*)x;
        float4 v0 = xv[idx * 2];
        float4 v1 = xv[idx * 2 + 1];
        v8bf o = { (bf16)v0.x, (bf16)v0.y, (bf16)v0.z, (bf16)v0.w,
                   (bf16)v1.x, (bf16)v1.y, (bf16)v1.z, (bf16)v1.w };
        *(v8bf*)(xbf + idx * 8) = o;
    }
}

// ---------------- K0b: weights -> transposed bf16 ----------------
__global__ void convert_w_kernel(const float* __restrict__ wqkv, const float* __restrict__ wout,
                                 bf16* __restrict__ Wt, bf16* __restrict__ WoT) {
    int idx = blockIdx.x * 256 + threadIdx.x;        // 786,432 threads
    Wt[idx] = (bf16)wqkv[(idx & 511) * 1536 + (idx >> 9)];
    if (idx < 262144) WoT[idx] = (bf16)wout[(idx & 511) * 512 + (idx >> 9)];
}

// ---------------- K1a: meta-MLP bias[h][i][j] ----------------
__global__ void bias_kernel(const float* __restrict__ rel_log, const float* __restrict__ w1,
                            const float* __restrict__ b1, const float* __restrict__ w2,
                            const float* __restrict__ b2, float* __restrict__ bias) {
    int p = blockIdx.x * 256 + threadIdx.x;          // (i,j) pair, 4096 total
    float ra = rel_log[p * 2 + 0];
    float rb = rel_log[p * 2 + 1];
    float acc[16];
    #pragma unroll
    for (int t = 0; t < 16; ++t) acc[t] = 0.f;
    for (int kk = 0; kk < 384; ++kk) {
        float hv = fmaxf(ra * w1[kk] + rb * w1[384 + kk] + b1[kk], 0.f);
        #pragma unroll
        for (int t = 0; t < 16; ++t) acc[t] += hv * w2[kk * 16 + t];
    }
    #pragma unroll
    for (int t = 0; t < 16; ++t) bias[t * 4096 + p] = acc[t] + b2[t];
}

// ---------------- K1b: comb swizzled for the SWAPPED (S^T) frag layout ----------------
// idx = (w*16+h)*4096 + (j*4+i)*256 + (lq*16+lm)*4 + r  maps to  p = q*64 + k,
// with q = i*16+lm, k = j*16+lq*4+r.
__global__ void comb_kernel(const float* __restrict__ bias, const float* __restrict__ mask,
                            float* __restrict__ comb) {
    int idx = blockIdx.x * 256 + threadIdx.x;        // 4,194,304 threads (16384 blocks)
    int t = idx & 4095, wh = idx >> 12;
    int w = wh >> 4, h = wh & 15;
    int ji = t >> 8, rem = t & 255;
    int j = ji >> 2, i = ji & 3;
    int q16 = rem >> 2, r = t & 3;
    int lq = q16 >> 4, lm = q16 & 15;
    int p = (i * 16 + lm) * 64 + j * 16 + lq * 4 + r;
    comb[idx] = bias[h * 4096 + p] + mask[w * 4096 + p];
}

// ---------------- K2: qkv GEMM, 2-phase dbuf global_load_lds, plain bf16 epilogue ----------------
// Tile 128x128, BK=32, 4 waves. Grid 6*W blocks (W/2 m-tiles x 12 nb); nb fastest after swizzle.
// Outputs (UNNORMALIZED): q_ws/k_ws [bw*16+h][n][dh] bf16, v_ws [bw*16+h][dh][n] bf16.
__global__ __launch_bounds__(256) void qkv_gemm_kernel(
    const bf16* __restrict__ xbf,   // [Mc][512] chunk rows, bf16
    const bf16* __restrict__ Wt,    // [1536][512]
    bf16* __restrict__ q_ws, bf16* __restrict__ k_ws, bf16* __restrict__ v_ws)
{
    __shared__ alignas(16) bf16 Alds[2][128 * 32];
    __shared__ alignas(16) bf16 Blds[2][128 * 32];
    const int bid = blockIdx.x, nwg = gridDim.x;
    const int wid = (bid & 7) * (nwg >> 3) + (bid >> 3);   // XCD-bijective (nwg%8==0)
    const int nb = wid % 12, mb = wid / 12;                // mb in [0, W/2)

    const int t = threadIdx.x;
    const int wv = t >> 6, lane = t & 63, lq = lane >> 4, lm = lane & 15;
    const int wr = wv >> 1, wc = wv & 1;

    const char* aBase = (const char*)xbf + (size_t)mb * 128 * 1024;
    const char* bBase = (const char*)Wt + (size_t)nb * 128 * 1024;

    auto stage = [&](int buf, int kt) {
        #pragma unroll
        for (int p = 0; p < 2; ++p) {
            int idx = (p * 4 + wv) * 1024 + lane * 16;     // byte offset in 8KB tile
            int row = idx >> 6, kb = idx & 63;
            __builtin_amdgcn_global_load_lds(
                (const __attribute__((address_space(1))) void*)(aBase + (size_t)row * 1024 + kt * 64 + kb),
                (__attribute__((address_space(3))) void*)((char*)Alds + buf * 8192 + (p * 4 + wv) * 1024),
                16, 0, 0);
            __builtin_amdgcn_global_load_lds(
                (const __attribute__((address_space(1))) void*)(bBase + (size_t)row * 1024 + kt * 64 + kb),
                (__attribute__((address_space(3))) void*)((char*)Blds + buf * 8192 + (p * 4 + wv) * 1024),
                16, 0, 0);
        }
    };

    v4f acc[4][4];
    #pragma unroll
    for (int i = 0; i < 4; ++i)
        #pragma unroll
        for (int j = 0; j < 4; ++j) acc[i][j] = v4f{0.f, 0.f, 0.f, 0.f};

    stage(0, 0);
    __syncthreads();
    int cur = 0;
    for (int kt = 0; kt < 16; ++kt) {
        if (kt < 15) stage(cur ^ 1, kt + 1);   // in flight during this tile's MFMA
        v8bf af[4], bfj[4];
        #pragma unroll
        for (int i = 0; i < 4; ++i)
            af[i] = *(const v8bf*)(&Alds[cur][0] + (wr * 64 + i * 16 + lm) * 32 + lq * 8);
        #pragma unroll
        for (int j = 0; j < 4; ++j)
            bfj[j] = *(const v8bf*)(&Blds[cur][0] + (wc * 64 + j * 16 + lm) * 32 + lq * 8);
        #pragma unroll
        for (int i = 0; i < 4; ++i)
            #pragma unroll
            for (int j = 0; j < 4; ++j)
                acc[i][j] = __builtin_amdgcn_mfma_f32_16x16x32_bf16(af[i], bfj[j], acc[i][j], 0, 0, 0);
        __syncthreads();                       // drains next tile's loads + joins waves
        cur ^= 1;
    }

    // epilogue (no norm): row n = i*16+lq*4+r (window bw=mb*2+wr), col = nb*128+wc*64+j*16+lm
    const int bw = mb * 2 + wr;
    if (nb < 8) {
        bf16* dst = (nb < 4) ? q_ws : k_ws;
        const int hbase = (nb & 3) * 4 + wc * 2;
        #pragma unroll
        for (int tpair = 0; tpair < 2; ++tpair) {
            const int h = hbase + tpair;
            #pragma unroll
            for (int i = 0; i < 4; ++i)
                #pragma unroll
                for (int r = 0; r < 4; ++r) {
                    int n = i * 16 + lq * 4 + r;
                    size_t base = ((size_t)(bw * 16 + h) * 64 + n) * 32;
                    dst[base + lm]      = (bf16)acc[i][2 * tpair][r];
                    dst[base + 16 + lm] = (bf16)acc[i][2 * tpair + 1][r];
                }
        }
    } else {
        #pragma unroll
        for (int j = 0; j < 4; ++j) {
            const int h = (nb - 8) * 4 + wc * 2 + (j >> 1);
            const int dh = (j & 1) * 16 + lm;
            #pragma unroll
            for (int i = 0; i < 4; ++i) {
                v4bf pv = { (bf16)acc[i][j][0], (bf16)acc[i][j][1],
                            (bf16)acc[i][j][2], (bf16)acc[i][j][3] };
                *(v4bf*)(v_ws + ((size_t)(bw * 16 + h) * 32 + dh) * 64 + i * 16 + lq * 4) = pv;
            }
        }
    }
}

// ---------------- K3: attention, swapped QK^T, frag-local norm, 1 head/wave ----------------
__global__ __launch_bounds__(256) void attn_kernel(
    const bf16* __restrict__ q_ws,   // [bw*16+h][64][32] unnormalized
    const bf16* __restrict__ k_ws,
    const bf16* __restrict__ v_ws,   // [bw*16+h][32][64]
    const float* __restrict__ comb,  // [64][16][4096] swizzled for S^T frags
    const float* __restrict__ tau,   // [16]
    int wofs,                        // chunk's first window
    bf16* __restrict__ attn_out)     // chunk slice, [rows][512]
{
    __shared__ alignas(16) bf16 P_all[4][64 * 72];
    const int blk = blockIdx.x;
    const int b = blk >> 2, g = blk & 3;
    const int tid = threadIdx.x;
    const int wv = tid >> 6, lane = tid & 63, lq = lane >> 4, lm = lane & 15;
    const int h = g * 4 + wv;
    const v4f z4 = {0.f, 0.f, 0.f, 0.f};

    bf16* P = P_all[wv];
    const size_t qk_base = (size_t)(b * 16 + h) * 64 * 32;
    const float* comb_hw = comb + ((size_t)(((wofs + b) & 63) * 16 + h)) * 4096
                                + (lq * 16 + lm) * 4;
    const float tau_h = tau[h];

    v8bf qf[4], kf[4];
    #pragma unroll
    for (int i = 0; i < 4; ++i)
        qf[i] = *(const v8bf*)(q_ws + qk_base + (i * 16 + lm) * 32 + lq * 8);
    #pragma unroll
    for (int j = 0; j < 4; ++j)
        kf[j] = *(const v8bf*)(k_ws + qk_base + (j * 16 + lm) * 32 + lq * 8);

    // frag-local L2 norms: 8 in-lane squares + 2 shfl over lq groups; tau folded into q-scale
    #pragma unroll
    for (int i = 0; i < 4; ++i) {
        float a = 0.f;
        #pragma unroll
        for (int e = 0; e < 8; ++e) { float f = (float)qf[i][e]; a = fmaf(f, f, a); }
        a += __shfl_xor(a, 16); a += __shfl_xor(a, 32);
        float sc = tau_h / fmaxf(sqrtf(a), 1e-12f);
        #pragma unroll
        for (int e = 0; e < 8; ++e) qf[i][e] = (bf16)((float)qf[i][e] * sc);
    }
    #pragma unroll
    for (int j = 0; j < 4; ++j) {
        float a = 0.f;
        #pragma unroll
        for (int e = 0; e < 8; ++e) { float f = (float)kf[j][e]; a = fmaf(f, f, a); }
        a += __shfl_xor(a, 16); a += __shfl_xor(a, 32);
        float sc = 1.0f / fmaxf(sqrtf(a), 1e-12f);
        #pragma unroll
        for (int e = 0; e < 8; ++e) kf[j][e] = (bf16)((float)kf[j][e] * sc);
    }

    // S^T = K̂ Q̂^T: lane holds (k = j*16+lq*4+r, q = i*16+lm)
    v4f st[4][4];
    #pragma unroll
    for (int j = 0; j < 4; ++j)
        #pragma unroll
        for (int i = 0; i < 4; ++i)
            st[j][i] = __builtin_amdgcn_mfma_f32_16x16x32_bf16(kf[j], qf[i], z4, 0, 0, 0);

    // + (bias+mask) in S^T frag layout
    #pragma unroll
    for (int j = 0; j < 4; ++j)
        #pragma unroll
        for (int i = 0; i < 4; ++i) {
            float4 cv = *(const float4*)(comb_hw + (j * 4 + i) * 256);
            st[j][i][0] += cv.x; st[j][i][1] += cv.y;
            st[j][i][2] += cv.z; st[j][i][3] += cv.w;
        }

    // softmax over k per q-col i: 16 in-lane + 2 shfl; fold 1/l into P; vectorized P store
    #pragma unroll
    for (int i = 0; i < 4; ++i) {
        float mx = st[0][i][0];
        #pragma unroll
        for (int j = 0; j < 4; ++j)
            #pragma unroll
            for (int r = 0; r < 4; ++r) mx = fmaxf(mx, st[j][i][r]);
        mx = fmaxf(mx, __shfl_xor(mx, 16));
        mx = fmaxf(mx, __shfl_xor(mx, 32));
        float sm = 0.f;
        #pragma unroll
        for (int j = 0; j < 4; ++j)
            #pragma unroll
            for (int r = 0; r < 4; ++r) {
                float e = __expf(st[j][i][r] - mx);
                st[j][i][r] = e; sm += e;
            }
        sm += __shfl_xor(sm, 16); sm += __shfl_xor(sm, 32);
        float rcp = 1.0f / sm;
        #pragma unroll
        for (int j = 0; j < 4; ++j) {
            v4bf pv = { (bf16)(st[j][i][0] * rcp), (bf16)(st[j][i][1] * rcp),
                        (bf16)(st[j][i][2] * rcp), (bf16)(st[j][i][3] * rcp) };
            *(v4bf*)(P + (i * 16 + lm) * 72 + j * 16 + lq * 4) = pv;
        }
    }

    // O = P̂ V (P already normalized): pf = P rows, vf = V^T rows
    const size_t v_base = (size_t)(b * 16 + h) * 32 * 64;
    v4f o[4][2];
    #pragma unroll
    for (int i = 0; i < 4; ++i)
        #pragma unroll
        for (int nt = 0; nt < 2; ++nt) o[i][nt] = z4;
    #pragma unroll
    for (int kk = 0; kk < 2; ++kk) {
        v8bf vf[2], pf[4];
        #pragma unroll
        for (int nt = 0; nt < 2; ++nt)
            vf[nt] = *(const v8bf*)(v_ws + v_base + (nt * 16 + lm) * 64 + kk * 32 + lq * 8);
        #pragma unroll
        for (int i = 0; i < 4; ++i)
            pf[i] = *(const v8bf*)(P + (i * 16 + lm) * 72 + kk * 32 + lq * 8);
        #pragma unroll
        for (int i = 0; i < 4; ++i)
            #pragma unroll
            for (int nt = 0; nt < 2; ++nt)
                o[i][nt] = __builtin_amdgcn_mfma_f32_16x16x32_bf16(pf[i], vf[nt], o[i][nt], 0, 0, 0);
    }
    #pragma unroll
    for (int i = 0; i < 4; ++i)
        #pragma unroll
        for (int nt = 0; nt < 2; ++nt)
            #pragma unroll
            for (int r = 0; r < 4; ++r)
                attn_out[(size_t)(b * 64 + i * 16 + lq * 4 + r) * 512 + h * 32 + nt * 16 + lm] =
                    (bf16)o[i][nt][r];
}

// ---------------- K4: out-projection GEMM, 2-phase dbuf ----------------
__global__ __launch_bounds__(256) void proj_gemm_kernel(
    const bf16* __restrict__ A,     // [131072][512] attn_out
    const bf16* __restrict__ Bt,    // [512][512] WoT
    const float* __restrict__ b_out,
    float* __restrict__ out)        // [131072][512]
{
    __shared__ alignas(16) bf16 Alds[2][128 * 32];
    __shared__ alignas(16) bf16 Blds[2][128 * 32];
    const int bid = blockIdx.x;                       // 4096 blocks
    const int wid = (bid & 7) * 512 + (bid >> 3);     // XCD swizzle
    const int mb = wid >> 2, nb = wid & 3;            // nb fastest: A-tile reuse
    const int tid = threadIdx.x;
    const int wv = tid >> 6, lane = tid & 63, lq = lane >> 4, lm = lane & 15;
    const int wr = wv >> 1, wc = wv & 1;

    const char* aBase = (const char*)A + (size_t)mb * 128 * 1024;
    const char* bBase = (const char*)Bt + (size_t)nb * 128 * 1024;

    auto stage = [&](int buf, int kt) {
        #pragma unroll
        for (int p = 0; p < 2; ++p) {
            int idx = (p * 4 + wv) * 1024 + lane * 16;
            int row = idx >> 6, kb = idx & 63;
            __builtin_amdgcn_global_load_lds(
                (const __attribute__((address_space(1))) void*)(aBase + (size_t)row * 1024 + kt * 64 + kb),
                (__attribute__((address_space(3))) void*)((char*)Alds + buf * 8192 + (p * 4 + wv) * 1024),
                16, 0, 0);
            __builtin_amdgcn_global_load_lds(
                (const __attribute__((address_space(1))) void*)(bBase + (size_t)row * 1024 + kt * 64 + kb),
                (__attribute__((address_space(3))) void*)((char*)Blds + buf * 8192 + (p * 4 + wv) * 1024),
                16, 0, 0);
        }
    };

    v4f acc[4][4];
    #pragma unroll
    for (int i = 0; i < 4; ++i)
        #pragma unroll
        for (int j = 0; j < 4; ++j) acc[i][j] = v4f{0.f, 0.f, 0.f, 0.f};

    stage(0, 0);
    __syncthreads();
    int cur = 0;
    for (int kt = 0; kt < 16; ++kt) {
        if (kt < 15) stage(cur ^ 1, kt + 1);
        v8bf af[4], bfj[4];
        #pragma unroll
        for (int i = 0; i < 4; ++i)
            af[i] = *(const v8bf*)(&Alds[cur][0] + (wr * 64 + i * 16 + lm) * 32 + lq * 8);
        #pragma unroll
        for (int j = 0; j < 4; ++j)
            bfj[j] = *(const v8bf*)(&Blds[cur][0] + (wc * 64 + j * 16 + lm) * 32 + lq * 8);
        #pragma unroll
        for (int i = 0; i < 4; ++i)
            #pragma unroll
            for (int j = 0; j < 4; ++j)
                acc[i][j] = __builtin_amdgcn_mfma_f32_16x16x32_bf16(af[i], bfj[j], acc[i][j], 0, 0, 0);
        __syncthreads();
        cur ^= 1;
    }

    #pragma unroll
    for (int j = 0; j < 4; ++j) {
        int col = nb * 128 + wc * 64 + j * 16 + lm;
        float bo = b_out[col];
        #pragma unroll
        for (int i = 0; i < 4; ++i)
            #pragma unroll
            for (int r = 0; r < 4; ++r)
                out[(size_t)(mb * 128 + wr * 64 + i * 16 + lq * 4 + r) * 512 + col] = acc[i][j][r] + bo;
    }
}

// ---------------- launch ----------------
extern "C" void kernel_launch(void* const* d_in, const int* in_sizes, int n_in,
                              void* d_out, int out_size, void* d_ws, size_t ws_size,
                              hipStream_t stream) {
    (void)in_sizes; (void)n_in; (void)out_size;
    const float* x       = (const float*)d_in[0];
    const float* mask    = (const float*)d_in[1];
    const float* w_qkv   = (const float*)d_in[2];
    const float* tau     = (const float*)d_in[3];
    const float* mlp_w1  = (const float*)d_in[4];
    const float* mlp_b1  = (const float*)d_in[5];
    const float* mlp_w2  = (const float*)d_in[6];
    const float* mlp_b2  = (const float*)d_in[7];
    const float* w_out   = (const float*)d_in[8];
    const float* b_out   = (const float*)d_in[9];
    const float* rel_log = (const float*)d_in[10];
    float* out = (float*)d_out;

    char* ws = (char*)d_ws;
    bf16*  Wt     = (bf16*)(ws);                     // 1,572,864 B
    bf16*  WoT    = (bf16*)(ws + 1572864);           //   524,288 B
    float* bias   = (float*)(ws + 2097152);          //   262,144 B
    float* comb   = (float*)(ws + 2359296);          //  16,777,216 B
    bf16*  shared = (bf16*)(ws + 19136512);          // 134,217,728 B  (xbf, later attn_out)
    char*  qkv_base = ws + 153354240;

    // W windows per chunk; qkv buffers 3*W*65536 B. ws top = 153,354,240 + 3*W*65536.
    // W=2048 -> 556 MB total; ws_size = 1 GiB (round-5 poison fill = 1.074e9 B).
    size_t avail = (ws_size > 153354240ULL) ? ws_size - 153354240ULL : 0;
    int W = 2048;
    while (W > 128 && (size_t)W * 196608ULL > avail) W >>= 1;
    const size_t qkbuf = (size_t)W * 65536;          // bytes each for q/k/v
    bf16* qb = (bf16*)qkv_base;
    bf16* kb = (bf16*)(qkv_base + qkbuf);
    bf16* vb = (bf16*)(qkv_base + 2 * qkbuf);

    convert_w_kernel<<<3072, 256, 0, stream>>>(w_qkv, w_out, Wt, WoT);
    bias_kernel<<<16, 256, 0, stream>>>(rel_log, mlp_w1, mlp_b1, mlp_w2, mlp_b2, bias);
    comb_kernel<<<16384, 256, 0, stream>>>(bias, mask, comb);
    convert_x_kernel<<<2048, 256, 0, stream>>>(x, shared);

    const int nchunk = 2048 / W;
    for (int c = 0; c < nchunk; ++c) {
        bf16* slice = shared + (size_t)c * W * 64 * 512;   // xbf for this chunk, then attn_out
        qkv_gemm_kernel<<<6 * W, 256, 0, stream>>>(slice, Wt, qb, kb, vb);
        attn_kernel<<<4 * W, 256, 0, stream>>>(qb, kb, vb, comb, tau, c * W, slice);
    }
    proj_gemm_kernel<<<4096, 256, 0, stream>>>(shared, WoT, b_out, out);
}

// Round 11
// 751.545 us; speedup vs baseline: 1.7459x; 1.0292x over previous
//
#include <hip/hip_runtime.h>
#include <hip/hip_bf16.h>

// WindowAttentionV2: B_NW=2048, N=64, DIM=512, NH=16, DH=32, HID=384, NW=64
// v9 = v8 (W=2048 single chunk, swapped QK^T attn, frag-local norm)
//      + counted-vmcnt pipeline (T4) in qkv/proj K-loops:
//      raw s_barrier + s_waitcnt vmcnt(4); prefetch never drained to 0 in steady state.

typedef __bf16 bf16;
typedef __bf16 v4bf __attribute__((ext_vector_type(4)));
typedef __bf16 v8bf __attribute__((ext_vector_type(8)));
typedef float  v4f  __attribute__((ext_vector_type(4)));

// ---------------- K0a: x fp32 -> bf16 (grid-stride) ----------------
__global__ void convert_x_kernel(const float* __restrict__ x, bf16* __restrict__ xbf) {
    const int stride = gridDim.x * 256;
    for (size_t idx = blockIdx.x * 256 + threadIdx.x; idx < 8388608; idx += stride) {
        const float4* xv = (const float4*)x;
        float4 v0 = xv[idx * 2];
        float4 v1 = xv[idx * 2 + 1];
        v8bf o = { (bf16)v0.x, (bf16)v0.y, (bf16)v0.z, (bf16)v0.w,
                   (bf16)v1.x, (bf16)v1.y, (bf16)v1.z, (bf16)v1.w };
        *(v8bf*)(xbf + idx * 8) = o;
    }
}

// ---------------- K0b: weights -> transposed bf16 ----------------
__global__ void convert_w_kernel(const float* __restrict__ wqkv, const float* __restrict__ wout,
                                 bf16* __restrict__ Wt, bf16* __restrict__ WoT) {
    int idx = blockIdx.x * 256 + threadIdx.x;        // 786,432 threads
    Wt[idx] = (bf16)wqkv[(idx & 511) * 1536 + (idx >> 9)];
    if (idx < 262144) WoT[idx] = (bf16)wout[(idx & 511) * 512 + (idx >> 9)];
}

// ---------------- K1a: meta-MLP bias[h][i][j] ----------------
__global__ void bias_kernel(const float* __restrict__ rel_log, const float* __restrict__ w1,
                            const float* __restrict__ b1, const float* __restrict__ w2,
                            const float* __restrict__ b2, float* __restrict__ bias) {
    int p = blockIdx.x * 256 + threadIdx.x;          // (i,j) pair, 4096 total
    float ra = rel_log[p * 2 + 0];
    float rb = rel_log[p * 2 + 1];
    float acc[16];
    #pragma unroll
    for (int t = 0; t < 16; ++t) acc[t] = 0.f;
    for (int kk = 0; kk < 384; ++kk) {
        float hv = fmaxf(ra * w1[kk] + rb * w1[384 + kk] + b1[kk], 0.f);
        #pragma unroll
        for (int t = 0; t < 16; ++t) acc[t] += hv * w2[kk * 16 + t];
    }
    #pragma unroll
    for (int t = 0; t < 16; ++t) bias[t * 4096 + p] = acc[t] + b2[t];
}

// ---------------- K1b: comb swizzled for the SWAPPED (S^T) frag layout ----------------
// idx = (w*16+h)*4096 + (j*4+i)*256 + (lq*16+lm)*4 + r  maps to  p = q*64 + k,
// with q = i*16+lm, k = j*16+lq*4+r.
__global__ void comb_kernel(const float* __restrict__ bias, const float* __restrict__ mask,
                            float* __restrict__ comb) {
    int idx = blockIdx.x * 256 + threadIdx.x;        // 4,194,304 threads (16384 blocks)
    int t = idx & 4095, wh = idx >> 12;
    int w = wh >> 4, h = wh & 15;
    int ji = t >> 8, rem = t & 255;
    int j = ji >> 2, i = ji & 3;
    int q16 = rem >> 2, r = t & 3;
    int lq = q16 >> 4, lm = q16 & 15;
    int p = (i * 16 + lm) * 64 + j * 16 + lq * 4 + r;
    comb[idx] = bias[h * 4096 + p] + mask[w * 4096 + p];
}

// ---------------- K2: qkv GEMM, counted-vmcnt 2-buffer pipeline ----------------
// Tile 128x128, BK=32, 4 waves. Grid 6*W blocks (W/2 m-tiles x 12 nb); nb fastest after swizzle.
// Outputs (UNNORMALIZED): q_ws/k_ws [bw*16+h][n][dh] bf16, v_ws [bw*16+h][dh][n] bf16.
__global__ __launch_bounds__(256) void qkv_gemm_kernel(
    const bf16* __restrict__ xbf,   // [Mc][512] chunk rows, bf16
    const bf16* __restrict__ Wt,    // [1536][512]
    bf16* __restrict__ q_ws, bf16* __restrict__ k_ws, bf16* __restrict__ v_ws)
{
    __shared__ alignas(16) bf16 Alds[2][128 * 32];
    __shared__ alignas(16) bf16 Blds[2][128 * 32];
    const int bid = blockIdx.x, nwg = gridDim.x;
    const int wid = (bid & 7) * (nwg >> 3) + (bid >> 3);   // XCD-bijective (nwg%8==0)
    const int nb = wid % 12, mb = wid / 12;                // mb in [0, W/2)

    const int t = threadIdx.x;
    const int wv = t >> 6, lane = t & 63, lq = lane >> 4, lm = lane & 15;
    const int wr = wv >> 1, wc = wv & 1;

    const char* aBase = (const char*)xbf + (size_t)mb * 128 * 1024;
    const char* bBase = (const char*)Wt + (size_t)nb * 128 * 1024;

    auto stage = [&](int buf, int kt) {   // 4 global_load_lds per thread (2 A + 2 B)
        #pragma unroll
        for (int p = 0; p < 2; ++p) {
            int idx = (p * 4 + wv) * 1024 + lane * 16;     // byte offset in 8KB tile
            int row = idx >> 6, kb = idx & 63;
            __builtin_amdgcn_global_load_lds(
                (const __attribute__((address_space(1))) void*)(aBase + (size_t)row * 1024 + kt * 64 + kb),
                (__attribute__((address_space(3))) void*)((char*)Alds + buf * 8192 + (p * 4 + wv) * 1024),
                16, 0, 0);
            __builtin_amdgcn_global_load_lds(
                (const __attribute__((address_space(1))) void*)(bBase + (size_t)row * 1024 + kt * 64 + kb),
                (__attribute__((address_space(3))) void*)((char*)Blds + buf * 8192 + (p * 4 + wv) * 1024),
                16, 0, 0);
        }
    };

    v4f acc[4][4];
    #pragma unroll
    for (int i = 0; i < 4; ++i)
        #pragma unroll
        for (int j = 0; j < 4; ++j) acc[i][j] = v4f{0.f, 0.f, 0.f, 0.f};

    stage(0, 0);
    #pragma unroll 1
    for (int kt = 0; kt < 16; ++kt) {
        if (kt < 15) {
            stage((kt + 1) & 1, kt + 1);               // next tile stays in flight across barriers
            asm volatile("s_waitcnt vmcnt(4)" ::: "memory");   // tile kt landed; kt+1 outstanding
        } else {
            asm volatile("s_waitcnt vmcnt(0)" ::: "memory");
        }
        __builtin_amdgcn_s_barrier();                  // publish tile kt
        __builtin_amdgcn_sched_barrier(0);
        const bf16* Ab = &Alds[kt & 1][0];
        const bf16* Bb = &Blds[kt & 1][0];
        v8bf af[4], bfj[4];
        #pragma unroll
        for (int i = 0; i < 4; ++i)
            af[i] = *(const v8bf*)(Ab + (wr * 64 + i * 16 + lm) * 32 + lq * 8);
        #pragma unroll
        for (int j = 0; j < 4; ++j)
            bfj[j] = *(const v8bf*)(Bb + (wc * 64 + j * 16 + lm) * 32 + lq * 8);
        #pragma unroll
        for (int i = 0; i < 4; ++i)
            #pragma unroll
            for (int j = 0; j < 4; ++j)
                acc[i][j] = __builtin_amdgcn_mfma_f32_16x16x32_bf16(af[i], bfj[j], acc[i][j], 0, 0, 0);
        __builtin_amdgcn_s_barrier();                  // reads done; buf may be overwritten next iter
    }

    // epilogue (no norm): row n = i*16+lq*4+r (window bw=mb*2+wr), col = nb*128+wc*64+j*16+lm
    const int bw = mb * 2 + wr;
    if (nb < 8) {
        bf16* dst = (nb < 4) ? q_ws : k_ws;
        const int hbase = (nb & 3) * 4 + wc * 2;
        #pragma unroll
        for (int tpair = 0; tpair < 2; ++tpair) {
            const int h = hbase + tpair;
            #pragma unroll
            for (int i = 0; i < 4; ++i)
                #pragma unroll
                for (int r = 0; r < 4; ++r) {
                    int n = i * 16 + lq * 4 + r;
                    size_t base = ((size_t)(bw * 16 + h) * 64 + n) * 32;
                    dst[base + lm]      = (bf16)acc[i][2 * tpair][r];
                    dst[base + 16 + lm] = (bf16)acc[i][2 * tpair + 1][r];
                }
        }
    } else {
        #pragma unroll
        for (int j = 0; j < 4; ++j) {
            const int h = (nb - 8) * 4 + wc * 2 + (j >> 1);
            const int dh = (j & 1) * 16 + lm;
            #pragma unroll
            for (int i = 0; i < 4; ++i) {
                v4bf pv = { (bf16)acc[i][j][0], (bf16)acc[i][j][1],
                            (bf16)acc[i][j][2], (bf16)acc[i][j][3] };
                *(v4bf*)(v_ws + ((size_t)(bw * 16 + h) * 32 + dh) * 64 + i * 16 + lq * 4) = pv;
            }
        }
    }
}

// ---------------- K3: attention, swapped QK^T, frag-local norm, 1 head/wave ----------------
__global__ __launch_bounds__(256) void attn_kernel(
    const bf16* __restrict__ q_ws,   // [bw*16+h][64][32] unnormalized
    const bf16* __restrict__ k_ws,
    const bf16* __restrict__ v_ws,   // [bw*16+h][32][64]
    const float* __restrict__ comb,  // [64][16][4096] swizzled for S^T frags
    const float* __restrict__ tau,   // [16]
    int wofs,                        // chunk's first window
    bf16* __restrict__ attn_out)     // chunk slice, [rows][512]
{
    __shared__ alignas(16) bf16 P_all[4][64 * 72];
    const int blk = blockIdx.x;
    const int b = blk >> 2, g = blk & 3;
    const int tid = threadIdx.x;
    const int wv = tid >> 6, lane = tid & 63, lq = lane >> 4, lm = lane & 15;
    const int h = g * 4 + wv;
    const v4f z4 = {0.f, 0.f, 0.f, 0.f};

    bf16* P = P_all[wv];
    const size_t qk_base = (size_t)(b * 16 + h) * 64 * 32;
    const float* comb_hw = comb + ((size_t)(((wofs + b) & 63) * 16 + h)) * 4096
                                + (lq * 16 + lm) * 4;
    const float tau_h = tau[h];

    v8bf qf[4], kf[4];
    #pragma unroll
    for (int i = 0; i < 4; ++i)
        qf[i] = *(const v8bf*)(q_ws + qk_base + (i * 16 + lm) * 32 + lq * 8);
    #pragma unroll
    for (int j = 0; j < 4; ++j)
        kf[j] = *(const v8bf*)(k_ws + qk_base + (j * 16 + lm) * 32 + lq * 8);

    // frag-local L2 norms: 8 in-lane squares + 2 shfl over lq groups; tau folded into q-scale
    #pragma unroll
    for (int i = 0; i < 4; ++i) {
        float a = 0.f;
        #pragma unroll
        for (int e = 0; e < 8; ++e) { float f = (float)qf[i][e]; a = fmaf(f, f, a); }
        a += __shfl_xor(a, 16); a += __shfl_xor(a, 32);
        float sc = tau_h / fmaxf(sqrtf(a), 1e-12f);
        #pragma unroll
        for (int e = 0; e < 8; ++e) qf[i][e] = (bf16)((float)qf[i][e] * sc);
    }
    #pragma unroll
    for (int j = 0; j < 4; ++j) {
        float a = 0.f;
        #pragma unroll
        for (int e = 0; e < 8; ++e) { float f = (float)kf[j][e]; a = fmaf(f, f, a); }
        a += __shfl_xor(a, 16); a += __shfl_xor(a, 32);
        float sc = 1.0f / fmaxf(sqrtf(a), 1e-12f);
        #pragma unroll
        for (int e = 0; e < 8; ++e) kf[j][e] = (bf16)((float)kf[j][e] * sc);
    }

    // S^T = K̂ Q̂^T: lane holds (k = j*16+lq*4+r, q = i*16+lm)
    v4f st[4][4];
    #pragma unroll
    for (int j = 0; j < 4; ++j)
        #pragma unroll
        for (int i = 0; i < 4; ++i)
            st[j][i] = __builtin_amdgcn_mfma_f32_16x16x32_bf16(kf[j], qf[i], z4, 0, 0, 0);

    // + (bias+mask) in S^T frag layout
    #pragma unroll
    for (int j = 0; j < 4; ++j)
        #pragma unroll
        for (int i = 0; i < 4; ++i) {
            float4 cv = *(const float4*)(comb_hw + (j * 4 + i) * 256);
            st[j][i][0] += cv.x; st[j][i][1] += cv.y;
            st[j][i][2] += cv.z; st[j][i][3] += cv.w;
        }

    // softmax over k per q-col i: 16 in-lane + 2 shfl; fold 1/l into P; vectorized P store
    #pragma unroll
    for (int i = 0; i < 4; ++i) {
        float mx = st[0][i][0];
        #pragma unroll
        for (int j = 0; j < 4; ++j)
            #pragma unroll
            for (int r = 0; r < 4; ++r) mx = fmaxf(mx, st[j][i][r]);
        mx = fmaxf(mx, __shfl_xor(mx, 16));
        mx = fmaxf(mx, __shfl_xor(mx, 32));
        float sm = 0.f;
        #pragma unroll
        for (int j = 0; j < 4; ++j)
            #pragma unroll
            for (int r = 0; r < 4; ++r) {
                float e = __expf(st[j][i][r] - mx);
                st[j][i][r] = e; sm += e;
            }
        sm += __shfl_xor(sm, 16); sm += __shfl_xor(sm, 32);
        float rcp = 1.0f / sm;
        #pragma unroll
        for (int j = 0; j < 4; ++j) {
            v4bf pv = { (bf16)(st[j][i][0] * rcp), (bf16)(st[j][i][1] * rcp),
                        (bf16)(st[j][i][2] * rcp), (bf16)(st[j][i][3] * rcp) };
            *(v4bf*)(P + (i * 16 + lm) * 72 + j * 16 + lq * 4) = pv;
        }
    }

    // O = P̂ V (P already normalized): pf = P rows, vf = V^T rows
    const size_t v_base = (size_t)(b * 16 + h) * 32 * 64;
    v4f o[4][2];
    #pragma unroll
    for (int i = 0; i < 4; ++i)
        #pragma unroll
        for (int nt = 0; nt < 2; ++nt) o[i][nt] = z4;
    #pragma unroll
    for (int kk = 0; kk < 2; ++kk) {
        v8bf vf[2], pf[4];
        #pragma unroll
        for (int nt = 0; nt < 2; ++nt)
            vf[nt] = *(const v8bf*)(v_ws + v_base + (nt * 16 + lm) * 64 + kk * 32 + lq * 8);
        #pragma unroll
        for (int i = 0; i < 4; ++i)
            pf[i] = *(const v8bf*)(P + (i * 16 + lm) * 72 + kk * 32 + lq * 8);
        #pragma unroll
        for (int i = 0; i < 4; ++i)
            #pragma unroll
            for (int nt = 0; nt < 2; ++nt)
                o[i][nt] = __builtin_amdgcn_mfma_f32_16x16x32_bf16(pf[i], vf[nt], o[i][nt], 0, 0, 0);
    }
    #pragma unroll
    for (int i = 0; i < 4; ++i)
        #pragma unroll
        for (int nt = 0; nt < 2; ++nt)
            #pragma unroll
            for (int r = 0; r < 4; ++r)
                attn_out[(size_t)(b * 64 + i * 16 + lq * 4 + r) * 512 + h * 32 + nt * 16 + lm] =
                    (bf16)o[i][nt][r];
}

// ---------------- K4: out-projection GEMM, counted-vmcnt 2-buffer pipeline ----------------
__global__ __launch_bounds__(256) void proj_gemm_kernel(
    const bf16* __restrict__ A,     // [131072][512] attn_out
    const bf16* __restrict__ Bt,    // [512][512] WoT
    const float* __restrict__ b_out,
    float* __restrict__ out)        // [131072][512]
{
    __shared__ alignas(16) bf16 Alds[2][128 * 32];
    __shared__ alignas(16) bf16 Blds[2][128 * 32];
    const int bid = blockIdx.x;                       // 4096 blocks
    const int wid = (bid & 7) * 512 + (bid >> 3);     // XCD swizzle
    const int mb = wid >> 2, nb = wid & 3;            // nb fastest: A-tile reuse
    const int tid = threadIdx.x;
    const int wv = tid >> 6, lane = tid & 63, lq = lane >> 4, lm = lane & 15;
    const int wr = wv >> 1, wc = wv & 1;

    const char* aBase = (const char*)A + (size_t)mb * 128 * 1024;
    const char* bBase = (const char*)Bt + (size_t)nb * 128 * 1024;

    auto stage = [&](int buf, int kt) {
        #pragma unroll
        for (int p = 0; p < 2; ++p) {
            int idx = (p * 4 + wv) * 1024 + lane * 16;
            int row = idx >> 6, kb = idx & 63;
            __builtin_amdgcn_global_load_lds(
                (const __attribute__((address_space(1))) void*)(aBase + (size_t)row * 1024 + kt * 64 + kb),
                (__attribute__((address_space(3))) void*)((char*)Alds + buf * 8192 + (p * 4 + wv) * 1024),
                16, 0, 0);
            __builtin_amdgcn_global_load_lds(
                (const __attribute__((address_space(1))) void*)(bBase + (size_t)row * 1024 + kt * 64 + kb),
                (__attribute__((address_space(3))) void*)((char*)Blds + buf * 8192 + (p * 4 + wv) * 1024),
                16, 0, 0);
        }
    };

    v4f acc[4][4];
    #pragma unroll
    for (int i = 0; i < 4; ++i)
        #pragma unroll
        for (int j = 0; j < 4; ++j) acc[i][j] = v4f{0.f, 0.f, 0.f, 0.f};

    stage(0, 0);
    #pragma unroll 1
    for (int kt = 0; kt < 16; ++kt) {
        if (kt < 15) {
            stage((kt + 1) & 1, kt + 1);
            asm volatile("s_waitcnt vmcnt(4)" ::: "memory");
        } else {
            asm volatile("s_waitcnt vmcnt(0)" ::: "memory");
        }
        __builtin_amdgcn_s_barrier();
        __builtin_amdgcn_sched_barrier(0);
        const bf16* Ab = &Alds[kt & 1][0];
        const bf16* Bb = &Blds[kt & 1][0];
        v8bf af[4], bfj[4];
        #pragma unroll
        for (int i = 0; i < 4; ++i)
            af[i] = *(const v8bf*)(Ab + (wr * 64 + i * 16 + lm) * 32 + lq * 8);
        #pragma unroll
        for (int j = 0; j < 4; ++j)
            bfj[j] = *(const v8bf*)(Bb + (wc * 64 + j * 16 + lm) * 32 + lq * 8);
        #pragma unroll
        for (int i = 0; i < 4; ++i)
            #pragma unroll
            for (int j = 0; j < 4; ++j)
                acc[i][j] = __builtin_amdgcn_mfma_f32_16x16x32_bf16(af[i], bfj[j], acc[i][j], 0, 0, 0);
        __builtin_amdgcn_s_barrier();
    }

    #pragma unroll
    for (int j = 0; j < 4; ++j) {
        int col = nb * 128 + wc * 64 + j * 16 + lm;
        float bo = b_out[col];
        #pragma unroll
        for (int i = 0; i < 4; ++i)
            #pragma unroll
            for (int r = 0; r < 4; ++r)
                out[(size_t)(mb * 128 + wr * 64 + i * 16 + lq * 4 + r) * 512 + col] = acc[i][j][r] + bo;
    }
}

// ---------------- launch ----------------
extern "C" void kernel_launch(void* const* d_in, const int* in_sizes, int n_in,
                              void* d_out, int out_size, void* d_ws, size_t ws_size,
                              hipStream_t stream) {
    (void)in_sizes; (void)n_in; (void)out_size;
    const float* x       = (const float*)d_in[0];
    const float* mask    = (const float*)d_in[1];
    const float* w_qkv   = (const float*)d_in[2];
    const float* tau     = (const float*)d_in[3];
    const float* mlp_w1  = (const float*)d_in[4];
    const float* mlp_b1  = (const float*)d_in[5];
    const float* mlp_w2  = (const float*)d_in[6];
    const float* mlp_b2  = (const float*)d_in[7];
    const float* w_out   = (const float*)d_in[8];
    const float* b_out   = (const float*)d_in[9];
    const float* rel_log = (const float*)d_in[10];
    float* out = (float*)d_out;

    char* ws = (char*)d_ws;
    bf16*  Wt     = (bf16*)(ws);                     // 1,572,864 B
    bf16*  WoT    = (bf16*)(ws + 1572864);           //   524,288 B
    float* bias   = (float*)(ws + 2097152);          //   262,144 B
    float* comb   = (float*)(ws + 2359296);          //  16,777,216 B
    bf16*  shared = (bf16*)(ws + 19136512);          // 134,217,728 B  (xbf, later attn_out)
    char*  qkv_base = ws + 153354240;

    // W windows per chunk; qkv buffers 3*W*65536 B. ws top = 153,354,240 + 3*W*65536.
    // W=2048 -> 556 MB total; ws_size = 1 GiB (round-5 poison fill = 1.074e9 B).
    size_t avail = (ws_size > 153354240ULL) ? ws_size - 153354240ULL : 0;
    int W = 2048;
    while (W > 128 && (size_t)W * 196608ULL > avail) W >>= 1;
    const size_t qkbuf = (size_t)W * 65536;          // bytes each for q/k/v
    bf16* qb = (bf16*)qkv_base;
    bf16* kb = (bf16*)(qkv_base + qkbuf);
    bf16* vb = (bf16*)(qkv_base + 2 * qkbuf);

    convert_w_kernel<<<3072, 256, 0, stream>>>(w_qkv, w_out, Wt, WoT);
    bias_kernel<<<16, 256, 0, stream>>>(rel_log, mlp_w1, mlp_b1, mlp_w2, mlp_b2, bias);
    comb_kernel<<<16384, 256, 0, stream>>>(bias, mask, comb);
    convert_x_kernel<<<2048, 256, 0, stream>>>(x, shared);

    const int nchunk = 2048 / W;
    for (int c = 0; c < nchunk; ++c) {
        bf16* slice = shared + (size_t)c * W * 64 * 512;   // xbf for this chunk, then attn_out
        qkv_gemm_kernel<<<6 * W, 256, 0, stream>>>(slice, Wt, qb, kb, vb);
        attn_kernel<<<4 * W, 256, 0, stream>>>(qb, kb, vb, comb, tau, c * W, slice);
    }
    proj_gemm_kernel<<<4096, 256, 0, stream>>>(shared, WoT, b_out, out);
}